// Round 2
// baseline (839.289 us; speedup 1.0000x reference)
//
#include <hip/hip_runtime.h>
#include <stdint.h>

#define LL 16384
#define NB 2
#define CIN 96
#define NLAT 256
#define COUT 96

__device__ __forceinline__ float b2f(unsigned short h) {
    return __uint_as_float(((unsigned int)h) << 16);
}
__device__ __forceinline__ unsigned short f2b(float f) {
    unsigned int u = __float_as_uint(f);
    unsigned int r = (u + 0x7FFFu + ((u >> 16) & 1u)) >> 16;
    return (unsigned short)r;
}

// ---------------- fold weights: WM[d*256+i][n] = sum_j yw[j][i] * mw[n][d*256+j]
__global__ __launch_bounds__(256) void k_foldw(
    const float* __restrict__ yw, const float* __restrict__ mw, const float* __restrict__ gw,
    float* __restrict__ WM, float* __restrict__ WG)
{
    __shared__ float At[64][68];
    __shared__ float Bt[64][68];
    int jt = blockIdx.x, nt = blockIdx.y, dz = blockIdx.z;
    int d = dz & 3, mat = dz >> 2;
    const float* src = mat ? gw : mw;
    float* dst = mat ? WG : WM;
    int j0 = jt * 64, n0 = nt * 64;
    int tid = threadIdx.x, tx = tid & 15, ty = tid >> 4;
    float acc[4][4] = {};
    for (int kt = 0; kt < 4; ++kt) {
        int i0 = kt * 64;
        for (int rep = 0; rep < 16; ++rep) {
            int idx = rep * 256 + tid;
            int r = idx >> 6, cq = idx & 63;
            At[r][cq] = yw[(size_t)(i0 + r) * 256 + j0 + cq];          // At[contract][j]
            Bt[cq][r] = src[(size_t)(n0 + r) * 1024 + d * 256 + i0 + cq]; // Bt[contract][n]
        }
        __syncthreads();
        for (int ii = 0; ii < 64; ++ii) {
            float4 a4 = *(const float4*)(&At[ii][ty * 4]);
            float4 b4 = *(const float4*)(&Bt[ii][tx * 4]);
            float av[4] = {a4.x, a4.y, a4.z, a4.w};
            float bv[4] = {b4.x, b4.y, b4.z, b4.w};
            for (int q = 0; q < 4; ++q)
                for (int p = 0; p < 4; ++p)
                    acc[q][p] = fmaf(av[q], bv[p], acc[q][p]);
        }
        __syncthreads();
    }
    for (int q = 0; q < 4; ++q) {
        int j = j0 + ty * 4 + q;
        for (int p = 0; p < 4; ++p) {
            int n = n0 + tx * 4 + p;
            dst[(size_t)(d * 256 + j) * 256 + n] = acc[q][p];
        }
    }
}

// folded biases: bm2[n] = mb[n] + sum_k mw[n][k]*yb[k%256]
__global__ void k_foldbias(const float* __restrict__ mw, const float* __restrict__ gw,
                           const float* __restrict__ mb, const float* __restrict__ gb,
                           const float* __restrict__ yb,
                           float* __restrict__ bm2, float* __restrict__ bg2)
{
    int t = threadIdx.x;          // 0..511
    int n = t & 255;
    const float* W = (t < 256) ? mw : gw;
    float acc = (t < 256) ? mb[n] : gb[n];
    for (int k = 0; k < 1024; ++k)
        acc = fmaf(W[(size_t)n * 1024 + k], yb[k & 255], acc);
    if (t < 256) bm2[n] = acc; else bg2[n] = acc;
}

// ---------------- in-projection: u,B,C,delta per position; emit a, bu=(1-a)*B*u (packed), C
__global__ __launch_bounds__(256) void k_proj(
    const float* __restrict__ x,
    const float* __restrict__ xw, const float* __restrict__ xb,
    const float* __restrict__ bcw, const float* __restrict__ bcb,
    const float* __restrict__ dw, const float* __restrict__ db,
    unsigned int* __restrict__ AB, unsigned short* __restrict__ C)
{
    __shared__ float Xt[96][68];
    __shared__ float Wt[96][68];
    int tid = threadIdx.x;
    int mt = blockIdx.x;          // 512 position tiles
    int nt = blockIdx.y;          // 16 channel tiles of 16
    int p0 = mt * 64;
    int b = p0 >> 14;
    int l0 = p0 & (LL - 1);
    int n0 = nt * 16;
    for (int rep = 0; rep < 24; ++rep) {
        int idx = rep * 256 + tid;
        int k = idx >> 6, i = idx & 63;
        Xt[k][i] = x[((size_t)(b * 96 + k)) * LL + l0 + i];
    }
    {
        int j = tid & 63;
        int kq = tid >> 6;
        int m = j >> 4, nn = j & 15;
        int n = n0 + nn;
        const float* row;
        if (m == 0)      row = xw + (size_t)n * 96;
        else if (m == 1) row = bcw + (size_t)n * 96;
        else if (m == 2) row = bcw + (size_t)(256 + n) * 96;
        else             row = dw + (size_t)n * 96;
        for (int kk = 0; kk < 24; ++kk) {
            int k = kq * 24 + kk;
            Wt[k][j] = row[k];
        }
    }
    __syncthreads();
    int tx = tid & 15, ty = tid >> 4;
    float acc[4][4] = {};
    for (int k = 0; k < 96; ++k) {
        float4 a4 = *(const float4*)(&Xt[k][ty * 4]);
        float av[4] = {a4.x, a4.y, a4.z, a4.w};
        float w0 = Wt[k][tx], w1 = Wt[k][tx + 16], w2 = Wt[k][tx + 32], w3 = Wt[k][tx + 48];
        for (int q = 0; q < 4; ++q) {
            acc[q][0] = fmaf(av[q], w0, acc[q][0]);
            acc[q][1] = fmaf(av[q], w1, acc[q][1]);
            acc[q][2] = fmaf(av[q], w2, acc[q][2]);
            acc[q][3] = fmaf(av[q], w3, acc[q][3]);
        }
    }
    int n = n0 + tx;
    float xbv = xb[n], bb = bcb[n], cb = bcb[256 + n], dbv = db[n];
    for (int q = 0; q < 4; ++q) {
        int l = l0 + ty * 4 + q;
        float u  = acc[q][0] + xbv;
        float Bm = acc[q][1] + bb;
        float Cm = acc[q][2] + cb;
        float dl = acc[q][3] + dbv;
        float a  = 1.0f / (1.0f + __expf(dl));   // exp(-softplus(d)) == sigmoid(-d)
        float bu = (1.0f - a) * Bm * u;
        size_t base = ((size_t)b * LL + l) * NLAT + n;
        AB[base] = (unsigned int)f2b(a) | ((unsigned int)f2b(bu) << 16);
        C[base]  = f2b(Cm);
    }
}

__device__ __forceinline__ int src_pos(int d, int t) {
    int s = (d >= 2) ? (LL - 1 - t) : t;
    return (d & 1) ? (((s & 127) << 7) | (s >> 7)) : s;   // dirs 1,3 traverse transposed order
}

// ---------------- scan pass 1: per-chunk aggregates (A_prod, B_acc)
__global__ __launch_bounds__(256) void k_scan1(
    const unsigned int* __restrict__ AB,
    float* __restrict__ AggA, float* __restrict__ AggB)
{
    int n = threadIdx.x;
    int c = blockIdx.x, d = blockIdx.y, b = blockIdx.z;
    float h = 0.f, Ap = 1.f;
    int t0 = c * 256;
#pragma unroll 4
    for (int i = 0; i < 256; ++i) {
        int ls = src_pos(d, t0 + i);
        unsigned int v = AB[((size_t)b * LL + ls) * NLAT + n];
        float a  = __uint_as_float(v << 16);
        float bu = __uint_as_float(v & 0xFFFF0000u);
        h = fmaf(a, h, bu);
        Ap *= a;
    }
    size_t o = (((size_t)b * 4 + d) * 64 + c) * NLAT + n;
    AggA[o] = Ap; AggB[o] = h;
}

// ---------------- scan pass 2: serial scan over 64 chunk aggregates
__global__ void k_scan2(const float* __restrict__ AggA, const float* __restrict__ AggB,
                        float* __restrict__ Hs)
{
    int n = threadIdx.x;
    int d = blockIdx.x, b = blockIdx.y;
    float h = 0.f;
    for (int c = 0; c < 64; ++c) {
        size_t o = (((size_t)b * 4 + d) * 64 + c) * NLAT + n;
        Hs[o] = h;
        h = fmaf(AggA[o], h, AggB[o]);
    }
}

// ---------------- scan pass 3: replay with true h_in, y = C*h
__global__ __launch_bounds__(256) void k_scan3(
    const unsigned int* __restrict__ AB, const unsigned short* __restrict__ C,
    const float* __restrict__ Hs, unsigned short* __restrict__ ys)
{
    int n = threadIdx.x;
    int c = blockIdx.x, d = blockIdx.y, b = blockIdx.z;
    size_t o = (((size_t)b * 4 + d) * 64 + c) * NLAT + n;
    float h = Hs[o];
    int t0 = c * 256;
    size_t ybase = (((size_t)b * 4 + d) * LL + t0) * NLAT + n;
#pragma unroll 4
    for (int i = 0; i < 256; ++i) {
        int ls = src_pos(d, t0 + i);
        size_t idx = ((size_t)b * LL + ls) * NLAT + n;
        unsigned int v = AB[idx];
        float a  = __uint_as_float(v << 16);
        float bu = __uint_as_float(v & 0xFFFF0000u);
        h = fmaf(a, h, bu);
        float y = b2f(C[idx]) * h;
        ys[ybase + (size_t)i * NLAT] = f2b(y);
    }
}

// ---------------- merge: z = (ys_cat@WM + bm2) * sigmoid(ys_cat@WG + bg2)
__global__ __launch_bounds__(256) void k_merge(
    const unsigned short* __restrict__ ys,
    const float* __restrict__ WM, const float* __restrict__ WG,
    const float* __restrict__ bm2, const float* __restrict__ bg2,
    unsigned short* __restrict__ z)
{
    __shared__ float At[64][68];
    __shared__ float Bt[64][68];
    int tid = threadIdx.x;
    int mt = blockIdx.x;          // 512 row tiles over 32768
    int nt = blockIdx.y;          // 8 tiles of 32 output channels
    int p0 = mt * 64;
    int b = p0 >> 14, l0 = p0 & (LL - 1);
    int n0 = nt * 32;
    int tx = tid & 15, ty = tid >> 4;
    float acc[4][4] = {};
    for (int kt = 0; kt < 16; ++kt) {
        int k0 = kt * 64;
        int d = k0 >> 8;
        int j0 = k0 & 255;
        for (int rep = 0; rep < 16; ++rep) {
            int idx = rep * 256 + tid;
            int r = idx >> 6, kk = idx & 63;
            At[kk][r] = b2f(ys[(((size_t)b * 4 + d) * LL + l0 + r) * NLAT + j0 + kk]);
        }
        for (int rep = 0; rep < 16; ++rep) {
            int idx = rep * 256 + tid;
            int kk = idx >> 6, cc = idx & 63;
            int mat = (cc >> 1) & 1;
            int n = n0 + ((cc >> 2) << 1) + (cc & 1);
            const float* srcw = mat ? WG : WM;
            Bt[kk][cc] = srcw[(size_t)(k0 + kk) * NLAT + n];
        }
        __syncthreads();
        for (int ii = 0; ii < 64; ++ii) {
            float4 a4 = *(const float4*)(&At[ii][ty * 4]);
            float4 b4 = *(const float4*)(&Bt[ii][tx * 4]);
            float av[4] = {a4.x, a4.y, a4.z, a4.w};
            float bv[4] = {b4.x, b4.y, b4.z, b4.w};
            for (int q = 0; q < 4; ++q)
                for (int p = 0; p < 4; ++p)
                    acc[q][p] = fmaf(av[q], bv[p], acc[q][p]);
        }
        __syncthreads();
    }
    int nA = n0 + 2 * tx, nBv = nA + 1;
    float bmA = bm2[nA], bmB = bm2[nBv], bgA = bg2[nA], bgB = bg2[nBv];
    for (int q = 0; q < 4; ++q) {
        int p = p0 + ty * 4 + q;
        float m0 = acc[q][0] + bmA, m1 = acc[q][1] + bmB;
        float g0 = acc[q][2] + bgA, g1 = acc[q][3] + bgB;
        float z0 = m0 / (1.f + __expf(-g0));
        float z1 = m1 / (1.f + __expf(-g1));
        unsigned int pack = (unsigned int)f2b(z0) | ((unsigned int)f2b(z1) << 16);
        *(unsigned int*)(&z[(size_t)p * NLAT + nA]) = pack;
    }
}

// ---------------- out projection: out[b][c][l] = z@ow.T + ob  (FLOAT32 out)
__global__ __launch_bounds__(256) void k_out(
    const unsigned short* __restrict__ z,
    const float* __restrict__ ow, const float* __restrict__ ob,
    float* __restrict__ out)
{
    __shared__ float Zt[64][68];
    __shared__ float Wt[64][100];
    int tid = threadIdx.x;
    int p0 = blockIdx.x * 64;
    int tx = tid & 15, ty = tid >> 4;
    float acc[4][6] = {};
    for (int kt = 0; kt < 4; ++kt) {
        int k0 = kt * 64;
        for (int rep = 0; rep < 16; ++rep) {
            int idx = rep * 256 + tid;
            int r = idx >> 6, kk = idx & 63;
            Zt[kk][r] = b2f(z[(size_t)(p0 + r) * NLAT + k0 + kk]);
        }
        for (int rep = 0; rep < 24; ++rep) {
            int idx = rep * 256 + tid;
            int cc = idx >> 6;      // 0..95
            int kk = idx & 63;
            Wt[kk][cc] = ow[(size_t)cc * NLAT + k0 + kk];
        }
        __syncthreads();
        for (int kk = 0; kk < 64; ++kk) {
            float zv[4];
            for (int rr = 0; rr < 4; ++rr) zv[rr] = Zt[kk][tx + 16 * rr];
            for (int m = 0; m < 6; ++m) {
                float wv = Wt[kk][ty + 16 * m];
                for (int rr = 0; rr < 4; ++rr) acc[rr][m] = fmaf(zv[rr], wv, acc[rr][m]);
            }
        }
        __syncthreads();
    }
    for (int m = 0; m < 6; ++m) {
        int cch = ty + 16 * m;
        float obv = ob[cch];
        for (int rr = 0; rr < 4; ++rr) {
            int p = p0 + tx + 16 * rr;
            int b = p >> 14, l = p & (LL - 1);
            out[((size_t)b * 96 + cch) * LL + l] = acc[rr][m] + obv;
        }
    }
}

extern "C" void kernel_launch(void* const* d_in, const int* in_sizes, int n_in,
                              void* d_out, int out_size, void* d_ws, size_t ws_size,
                              hipStream_t stream) {
    (void)in_sizes; (void)n_in; (void)out_size; (void)ws_size;
    const float* x   = (const float*)d_in[0];
    const float* xw  = (const float*)d_in[1];
    const float* xb  = (const float*)d_in[2];
    const float* bcw = (const float*)d_in[3];
    const float* bcb = (const float*)d_in[4];
    const float* dw  = (const float*)d_in[5];
    const float* db  = (const float*)d_in[6];
    const float* yw  = (const float*)d_in[7];
    const float* yb  = (const float*)d_in[8];
    const float* mw  = (const float*)d_in[9];
    const float* mb  = (const float*)d_in[10];
    const float* gw  = (const float*)d_in[11];
    const float* gb  = (const float*)d_in[12];
    const float* ow  = (const float*)d_in[13];
    const float* ob  = (const float*)d_in[14];
    float* out = (float*)d_out;

    char* ws = (char*)d_ws;
    size_t off = 0;
    auto alloc = [&](size_t bytes) -> void* {
        void* p = ws + off;
        off += (bytes + 255) & ~(size_t)255;
        return p;
    };
    // total ws use: ~138 MB
    unsigned int*   AB  = (unsigned int*)  alloc((size_t)NB * LL * NLAT * 4);  // 33.6 MB
    unsigned short* C   = (unsigned short*)alloc((size_t)NB * LL * NLAT * 2);  // 16.8 MB
    unsigned short* YS  = (unsigned short*)alloc((size_t)NB * 4 * LL * NLAT * 2); // 67 MB
    unsigned short* Z   = (unsigned short*)alloc((size_t)NB * LL * NLAT * 2);  // 16.8 MB
    float* WM   = (float*)alloc((size_t)1024 * 256 * 4);
    float* WG   = (float*)alloc((size_t)1024 * 256 * 4);
    float* BM2  = (float*)alloc(256 * 4);
    float* BG2  = (float*)alloc(256 * 4);
    float* AggA = (float*)alloc((size_t)NB * 4 * 64 * NLAT * 4);
    float* AggB = (float*)alloc((size_t)NB * 4 * 64 * NLAT * 4);
    float* HS   = (float*)alloc((size_t)NB * 4 * 64 * NLAT * 4);

    k_foldw   <<<dim3(4, 4, 8),   256, 0, stream>>>(yw, mw, gw, WM, WG);
    k_foldbias<<<1,               512, 0, stream>>>(mw, gw, mb, gb, yb, BM2, BG2);
    k_proj    <<<dim3(512, 16),   256, 0, stream>>>(x, xw, xb, bcw, bcb, dw, db, AB, C);
    k_scan1   <<<dim3(64, 4, NB), 256, 0, stream>>>(AB, AggA, AggB);
    k_scan2   <<<dim3(4, NB),     256, 0, stream>>>(AggA, AggB, HS);
    k_scan3   <<<dim3(64, 4, NB), 256, 0, stream>>>(AB, C, HS, YS);
    k_merge   <<<dim3(512, 8),    256, 0, stream>>>(YS, WM, WG, BM2, BG2, Z);
    k_out     <<<512,             256, 0, stream>>>(Z, ow, ob, out);
}

// Round 3
// 411.929 us; speedup vs baseline: 2.0375x; 2.0375x over previous
//
#include <hip/hip_runtime.h>
#include <stdint.h>

#define LL 16384
#define NB 2
#define CIN 96
#define NLAT 256
#define COUT 96

typedef __attribute__((ext_vector_type(8))) short short8v;
typedef __attribute__((ext_vector_type(4))) float float4v;

__device__ __forceinline__ float b2f(unsigned short h) {
    return __uint_as_float(((unsigned int)h) << 16);
}
__device__ __forceinline__ unsigned short f2b(float f) {
    unsigned int u = __float_as_uint(f);
    unsigned int r = (u + 0x7FFFu + ((u >> 16) & 1u)) >> 16;
    return (unsigned short)r;
}

#define GLL16(g, s) __builtin_amdgcn_global_load_lds( \
    (const __attribute__((address_space(1))) unsigned int*)(g), \
    (__attribute__((address_space(3))) unsigned int*)(s), 16, 0, 0)

// ---------------- fold weights into bf16 transposed WBT[n'][k]:
//   n' = mat*256 + n (mat 0 = merge, 1 = gate), k = d*256 + i
//   WBT[n'][k] = sum_j yw[j][i] * (mat?gw:mw)[n][d*256+j]
__global__ __launch_bounds__(256) void k_foldw(
    const float* __restrict__ yw, const float* __restrict__ mw, const float* __restrict__ gw,
    unsigned short* __restrict__ WBT)
{
    __shared__ float At[64][68];
    __shared__ float Bt[64][68];
    int jt = blockIdx.x, nt = blockIdx.y, dz = blockIdx.z;
    int d = dz & 3, mat = dz >> 2;
    const float* src = mat ? gw : mw;
    int j0 = jt * 64, n0 = nt * 64;
    int tid = threadIdx.x, tx = tid & 15, ty = tid >> 4;
    float acc[4][4] = {};
    for (int kt = 0; kt < 4; ++kt) {
        int i0 = kt * 64;
        for (int rep = 0; rep < 16; ++rep) {
            int idx = rep * 256 + tid;
            int r = idx >> 6, cq = idx & 63;
            At[r][cq] = yw[(size_t)(i0 + r) * 256 + j0 + cq];          // At[contract][i_out]
            Bt[cq][r] = src[(size_t)(n0 + r) * 1024 + d * 256 + i0 + cq]; // Bt[contract][n]
        }
        __syncthreads();
        for (int ii = 0; ii < 64; ++ii) {
            float4 a4 = *(const float4*)(&At[ii][ty * 4]);
            float4 b4 = *(const float4*)(&Bt[ii][tx * 4]);
            float av[4] = {a4.x, a4.y, a4.z, a4.w};
            float bv[4] = {b4.x, b4.y, b4.z, b4.w};
            for (int q = 0; q < 4; ++q)
                for (int p = 0; p < 4; ++p)
                    acc[q][p] = fmaf(av[q], bv[p], acc[q][p]);
        }
        __syncthreads();
    }
    for (int q = 0; q < 4; ++q) {
        int k = d * 256 + j0 + ty * 4 + q;   // folded K index
        for (int p = 0; p < 4; ++p) {
            int n = n0 + tx * 4 + p;
            WBT[(size_t)(mat * 256 + n) * 1024 + k] = f2b(acc[q][p]);
        }
    }
}

// folded biases: bm2[n] = mb[n] + sum_k mw[n][k]*yb[k%256]
__global__ void k_foldbias(const float* __restrict__ mw, const float* __restrict__ gw,
                           const float* __restrict__ mb, const float* __restrict__ gb,
                           const float* __restrict__ yb,
                           float* __restrict__ bm2, float* __restrict__ bg2)
{
    int t = threadIdx.x;          // 0..511
    int n = t & 255;
    const float* W = (t < 256) ? mw : gw;
    float acc = (t < 256) ? mb[n] : gb[n];
    for (int k = 0; k < 1024; ++k)
        acc = fmaf(W[(size_t)n * 1024 + k], yb[k & 255], acc);
    if (t < 256) bm2[n] = acc; else bg2[n] = acc;
}

// ---------------- in-projection: u,B,C,delta per position; emit a, bu=(1-a)*B*u (packed), C
__global__ __launch_bounds__(256) void k_proj(
    const float* __restrict__ x,
    const float* __restrict__ xw, const float* __restrict__ xb,
    const float* __restrict__ bcw, const float* __restrict__ bcb,
    const float* __restrict__ dw, const float* __restrict__ db,
    unsigned int* __restrict__ AB, unsigned short* __restrict__ C)
{
    __shared__ float Xt[96][68];
    __shared__ float Wt[96][68];
    int tid = threadIdx.x;
    int mt = blockIdx.x;          // 512 position tiles
    int nt = blockIdx.y;          // 16 channel tiles of 16
    int p0 = mt * 64;
    int b = p0 >> 14;
    int l0 = p0 & (LL - 1);
    int n0 = nt * 16;
    for (int rep = 0; rep < 24; ++rep) {
        int idx = rep * 256 + tid;
        int k = idx >> 6, i = idx & 63;
        Xt[k][i] = x[((size_t)(b * 96 + k)) * LL + l0 + i];
    }
    {
        int j = tid & 63;
        int kq = tid >> 6;
        int m = j >> 4, nn = j & 15;
        int n = n0 + nn;
        const float* row;
        if (m == 0)      row = xw + (size_t)n * 96;
        else if (m == 1) row = bcw + (size_t)n * 96;
        else if (m == 2) row = bcw + (size_t)(256 + n) * 96;
        else             row = dw + (size_t)n * 96;
        for (int kk = 0; kk < 24; ++kk) {
            int k = kq * 24 + kk;
            Wt[k][j] = row[k];
        }
    }
    __syncthreads();
    int tx = tid & 15, ty = tid >> 4;
    float acc[4][4] = {};
    for (int k = 0; k < 96; ++k) {
        float4 a4 = *(const float4*)(&Xt[k][ty * 4]);
        float av[4] = {a4.x, a4.y, a4.z, a4.w};
        float w0 = Wt[k][tx], w1 = Wt[k][tx + 16], w2 = Wt[k][tx + 32], w3 = Wt[k][tx + 48];
        for (int q = 0; q < 4; ++q) {
            acc[q][0] = fmaf(av[q], w0, acc[q][0]);
            acc[q][1] = fmaf(av[q], w1, acc[q][1]);
            acc[q][2] = fmaf(av[q], w2, acc[q][2]);
            acc[q][3] = fmaf(av[q], w3, acc[q][3]);
        }
    }
    int n = n0 + tx;
    float xbv = xb[n], bb = bcb[n], cb = bcb[256 + n], dbv = db[n];
    for (int q = 0; q < 4; ++q) {
        int l = l0 + ty * 4 + q;
        float u  = acc[q][0] + xbv;
        float Bm = acc[q][1] + bb;
        float Cm = acc[q][2] + cb;
        float dl = acc[q][3] + dbv;
        float a  = 1.0f / (1.0f + __expf(dl));   // exp(-softplus(d)) == sigmoid(-d)
        float bu = (1.0f - a) * Bm * u;
        size_t base = ((size_t)b * LL + l) * NLAT + n;
        AB[base] = (unsigned int)f2b(a) | ((unsigned int)f2b(bu) << 16);
        C[base]  = f2b(Cm);
    }
}

__device__ __forceinline__ int src_pos(int d, int t) {
    int s = (d >= 2) ? (LL - 1 - t) : t;
    return (d & 1) ? (((s & 127) << 7) | (s >> 7)) : s;   // dirs 1,3 traverse transposed order
}

// ---------------- scan pass 1: per-chunk aggregates (A_prod, B_acc)
__global__ __launch_bounds__(256) void k_scan1(
    const unsigned int* __restrict__ AB,
    float* __restrict__ AggA, float* __restrict__ AggB)
{
    int n = threadIdx.x;
    int c = blockIdx.x, d = blockIdx.y, b = blockIdx.z;
    float h = 0.f, Ap = 1.f;
    int t0 = c * 256;
#pragma unroll 4
    for (int i = 0; i < 256; ++i) {
        int ls = src_pos(d, t0 + i);
        unsigned int v = AB[((size_t)b * LL + ls) * NLAT + n];
        float a  = __uint_as_float(v << 16);
        float bu = __uint_as_float(v & 0xFFFF0000u);
        h = fmaf(a, h, bu);
        Ap *= a;
    }
    size_t o = (((size_t)b * 4 + d) * 64 + c) * NLAT + n;
    AggA[o] = Ap; AggB[o] = h;
}

// ---------------- scan pass 2: serial scan over 64 chunk aggregates
__global__ void k_scan2(const float* __restrict__ AggA, const float* __restrict__ AggB,
                        float* __restrict__ Hs)
{
    int n = threadIdx.x;
    int d = blockIdx.x, b = blockIdx.y;
    float h = 0.f;
    for (int c = 0; c < 64; ++c) {
        size_t o = (((size_t)b * 4 + d) * 64 + c) * NLAT + n;
        Hs[o] = h;
        h = fmaf(AggA[o], h, AggB[o]);
    }
}

// ---------------- scan pass 3: replay with true h_in, y = C*h
__global__ __launch_bounds__(256) void k_scan3(
    const unsigned int* __restrict__ AB, const unsigned short* __restrict__ C,
    const float* __restrict__ Hs, unsigned short* __restrict__ ys)
{
    int n = threadIdx.x;
    int c = blockIdx.x, d = blockIdx.y, b = blockIdx.z;
    size_t o = (((size_t)b * 4 + d) * 64 + c) * NLAT + n;
    float h = Hs[o];
    int t0 = c * 256;
    size_t ybase = (((size_t)b * 4 + d) * LL + t0) * NLAT + n;
#pragma unroll 4
    for (int i = 0; i < 256; ++i) {
        int ls = src_pos(d, t0 + i);
        size_t idx = ((size_t)b * LL + ls) * NLAT + n;
        unsigned int v = AB[idx];
        float a  = __uint_as_float(v << 16);
        float bu = __uint_as_float(v & 0xFFFF0000u);
        h = fmaf(a, h, bu);
        float y = b2f(C[idx]) * h;
        ys[ybase + (size_t)i * NLAT] = f2b(y);
    }
}

// ---------------- merge (MFMA bf16): z = (ys_cat@WM + bm2) * sigmoid(ys_cat@WG + bg2)
// A = ys (M=32768, K=1024 as d*256+j), B = WBT[n'][k] (bf16, n'=mat*256+n).
// Block: 128 rows x 64 n-cols x {M,G}. 4 waves, each 32 rows x 64 cols x 2 mats.
// m97 structure: BK=32, global_load_lds(16B), single LDS buffer, 2 barriers/K-step.
__global__ __launch_bounds__(256) void k_merge_mfma(
    const unsigned short* __restrict__ ys,
    const unsigned short* __restrict__ WBT,
    const float* __restrict__ bm2, const float* __restrict__ bg2,
    unsigned short* __restrict__ z)
{
    __shared__ unsigned short smA[128 * 32];   // [row][k] bf16, 8 KB
    __shared__ unsigned short smB[128 * 32];   // [colInTile][k] bf16, 8 KB (64 WM + 64 WG)
    int tid = threadIdx.x;
    int w = tid >> 6, l = tid & 63;
    int mt = blockIdx.x;          // 0..255 row tiles
    int nt = blockIdx.y;          // 0..3 n tiles of 64
    int p0 = mt * 128;
    int b4 = (p0 >> 14) * 4;
    int l0 = p0 & (LL - 1);
    int n0 = nt * 64;

    int rowA = tid >> 2;          // 0..63 (A rows per staging load)
    int chA  = tid & 3;           // 16B chunk within 64B row
    int laneRow = l & 15;
    int laneK   = l >> 4;

    float4v accM[2][4], accG[2][4];
#pragma unroll
    for (int i = 0; i < 2; ++i)
#pragma unroll
        for (int j = 0; j < 4; ++j) { accM[i][j] = (float4v)0.f; accG[i][j] = (float4v)0.f; }

    for (int kt = 0; kt < 32; ++kt) {
        int d = kt >> 3;
        int j0k = (kt & 7) * 32;
        const unsigned short* gA = ys + (((size_t)(b4 + d)) * LL + l0 + rowA) * 256 + j0k + chA * 8;
        const unsigned short* gB = WBT + ((size_t)(n0 + rowA)) * 1024 + kt * 32 + chA * 8;
        GLL16(gA,              smA + tid * 8);
        GLL16(gA + 64 * 256,   smA + 2048 + tid * 8);
        GLL16(gB,              smB + tid * 8);
        GLL16(gB + 256 * 1024, smB + 2048 + tid * 8);
        __syncthreads();

        short8v a0 = *(const short8v*)(&smA[(w * 32 + laneRow) * 32 + laneK * 8]);
        short8v a1 = *(const short8v*)(&smA[(w * 32 + 16 + laneRow) * 32 + laneK * 8]);
#pragma unroll
        for (int nr = 0; nr < 4; ++nr) {
            short8v bm_ = *(const short8v*)(&smB[(nr * 16 + laneRow) * 32 + laneK * 8]);
            short8v bg_ = *(const short8v*)(&smB[(64 + nr * 16 + laneRow) * 32 + laneK * 8]);
            accM[0][nr] = __builtin_amdgcn_mfma_f32_16x16x32_bf16(a0, bm_, accM[0][nr], 0, 0, 0);
            accM[1][nr] = __builtin_amdgcn_mfma_f32_16x16x32_bf16(a1, bm_, accM[1][nr], 0, 0, 0);
            accG[0][nr] = __builtin_amdgcn_mfma_f32_16x16x32_bf16(a0, bg_, accG[0][nr], 0, 0, 0);
            accG[1][nr] = __builtin_amdgcn_mfma_f32_16x16x32_bf16(a1, bg_, accG[1][nr], 0, 0, 0);
        }
        __syncthreads();
    }

    int lr = l >> 4, lc = l & 15;
#pragma unroll
    for (int mr = 0; mr < 2; ++mr) {
#pragma unroll
        for (int nr = 0; nr < 4; ++nr) {
            int n = n0 + nr * 16 + lc;
            float bmv = bm2[n], bgv = bg2[n];
#pragma unroll
            for (int q = 0; q < 4; ++q) {
                int p = p0 + w * 32 + mr * 16 + lr * 4 + q;
                float m = accM[mr][nr][q] + bmv;
                float g = accG[mr][nr][q] + bgv;
                float zv = m / (1.f + __expf(-g));
                z[(size_t)p * NLAT + n] = f2b(zv);
            }
        }
    }
}

// ---------------- out projection: out[b][c][l] = z@ow.T + ob  (FLOAT32 out)
__global__ __launch_bounds__(256) void k_out(
    const unsigned short* __restrict__ z,
    const float* __restrict__ ow, const float* __restrict__ ob,
    float* __restrict__ out)
{
    __shared__ float Zt[64][68];
    __shared__ float Wt[64][100];
    int tid = threadIdx.x;
    int p0 = blockIdx.x * 64;
    int tx = tid & 15, ty = tid >> 4;
    float acc[4][6] = {};
    for (int kt = 0; kt < 4; ++kt) {
        int k0 = kt * 64;
        for (int rep = 0; rep < 16; ++rep) {
            int idx = rep * 256 + tid;
            int r = idx >> 6, kk = idx & 63;
            Zt[kk][r] = b2f(z[(size_t)(p0 + r) * NLAT + k0 + kk]);
        }
        for (int rep = 0; rep < 24; ++rep) {
            int idx = rep * 256 + tid;
            int cc = idx >> 6;      // 0..95
            int kk = idx & 63;
            Wt[kk][cc] = ow[(size_t)cc * NLAT + k0 + kk];
        }
        __syncthreads();
        for (int kk = 0; kk < 64; ++kk) {
            float zv[4];
            for (int rr = 0; rr < 4; ++rr) zv[rr] = Zt[kk][tx + 16 * rr];
            for (int m = 0; m < 6; ++m) {
                float wv = Wt[kk][ty + 16 * m];
                for (int rr = 0; rr < 4; ++rr) acc[rr][m] = fmaf(zv[rr], wv, acc[rr][m]);
            }
        }
        __syncthreads();
    }
    for (int m = 0; m < 6; ++m) {
        int cch = ty + 16 * m;
        float obv = ob[cch];
        for (int rr = 0; rr < 4; ++rr) {
            int p = p0 + tx + 16 * rr;
            int b = p >> 14, l = p & (LL - 1);
            out[((size_t)b * 96 + cch) * LL + l] = acc[rr][m] + obv;
        }
    }
}

extern "C" void kernel_launch(void* const* d_in, const int* in_sizes, int n_in,
                              void* d_out, int out_size, void* d_ws, size_t ws_size,
                              hipStream_t stream) {
    (void)in_sizes; (void)n_in; (void)out_size; (void)ws_size;
    const float* x   = (const float*)d_in[0];
    const float* xw  = (const float*)d_in[1];
    const float* xb  = (const float*)d_in[2];
    const float* bcw = (const float*)d_in[3];
    const float* bcb = (const float*)d_in[4];
    const float* dw  = (const float*)d_in[5];
    const float* db  = (const float*)d_in[6];
    const float* yw  = (const float*)d_in[7];
    const float* yb  = (const float*)d_in[8];
    const float* mw  = (const float*)d_in[9];
    const float* mb  = (const float*)d_in[10];
    const float* gw  = (const float*)d_in[11];
    const float* gb  = (const float*)d_in[12];
    const float* ow  = (const float*)d_in[13];
    const float* ob  = (const float*)d_in[14];
    float* out = (float*)d_out;

    char* ws = (char*)d_ws;
    size_t off = 0;
    auto alloc = [&](size_t bytes) -> void* {
        void* p = ws + off;
        off += (bytes + 255) & ~(size_t)255;
        return p;
    };
    unsigned int*   AB  = (unsigned int*)  alloc((size_t)NB * LL * NLAT * 4);     // 33.6 MB
    unsigned short* C   = (unsigned short*)alloc((size_t)NB * LL * NLAT * 2);     // 16.8 MB
    unsigned short* YS  = (unsigned short*)alloc((size_t)NB * 4 * LL * NLAT * 2); // 67 MB
    unsigned short* Z   = (unsigned short*)alloc((size_t)NB * LL * NLAT * 2);     // 16.8 MB
    unsigned short* WBT = (unsigned short*)alloc((size_t)512 * 1024 * 2);         // 1 MB bf16
    float* BM2  = (float*)alloc(256 * 4);
    float* BG2  = (float*)alloc(256 * 4);
    float* AggA = (float*)alloc((size_t)NB * 4 * 64 * NLAT * 4);
    float* AggB = (float*)alloc((size_t)NB * 4 * 64 * NLAT * 4);
    float* HS   = (float*)alloc((size_t)NB * 4 * 64 * NLAT * 4);

    k_foldw     <<<dim3(4, 4, 8),   256, 0, stream>>>(yw, mw, gw, WBT);
    k_foldbias  <<<1,               512, 0, stream>>>(mw, gw, mb, gb, yb, BM2, BG2);
    k_proj      <<<dim3(512, 16),   256, 0, stream>>>(x, xw, xb, bcw, bcb, dw, db, AB, C);
    k_scan1     <<<dim3(64, 4, NB), 256, 0, stream>>>(AB, AggA, AggB);
    k_scan2     <<<dim3(4, NB),     256, 0, stream>>>(AggA, AggB, HS);
    k_scan3     <<<dim3(64, 4, NB), 256, 0, stream>>>(AB, C, HS, YS);
    k_merge_mfma<<<dim3(256, 4),    256, 0, stream>>>(YS, WBT, BM2, BG2, Z);
    k_out       <<<512,             256, 0, stream>>>(Z, ow, ob, out);
}

// Round 5
// 353.052 us; speedup vs baseline: 2.3772x; 1.1668x over previous
//
#include <hip/hip_runtime.h>
#include <stdint.h>

#define LL 16384
#define NB 2
#define CIN 96
#define NLAT 256
#define COUT 96

typedef __attribute__((ext_vector_type(8))) short short8v;
typedef __attribute__((ext_vector_type(4))) float float4v;

__device__ __forceinline__ float b2f(unsigned short h) {
    return __uint_as_float(((unsigned int)h) << 16);
}
__device__ __forceinline__ unsigned short f2b(float f) {
    unsigned int u = __float_as_uint(f);
    unsigned int r = (u + 0x7FFFu + ((u >> 16) & 1u)) >> 16;
    return (unsigned short)r;
}

#define GLL16(g, s) __builtin_amdgcn_global_load_lds( \
    (const __attribute__((address_space(1))) unsigned int*)(g), \
    (__attribute__((address_space(3))) unsigned int*)(s), 16, 0, 0)

// ---------------- fold weights into bf16 transposed WBT[n'][k]:
//   n' = mat*256 + n (mat 0 = merge, 1 = gate), k = d*256 + i
//   WBT[n'][k] = sum_j yw[j][i] * (mat?gw:mw)[n][d*256+j]
__global__ __launch_bounds__(256) void k_foldw(
    const float* __restrict__ yw, const float* __restrict__ mw, const float* __restrict__ gw,
    unsigned short* __restrict__ WBT)
{
    __shared__ float At[64][68];
    __shared__ float Bt[64][68];
    int jt = blockIdx.x, nt = blockIdx.y, dz = blockIdx.z;
    int d = dz & 3, mat = dz >> 2;
    const float* src = mat ? gw : mw;
    int j0 = jt * 64, n0 = nt * 64;
    int tid = threadIdx.x, tx = tid & 15, ty = tid >> 4;
    float acc[4][4] = {};
    for (int kt = 0; kt < 4; ++kt) {
        int i0 = kt * 64;
        for (int rep = 0; rep < 16; ++rep) {
            int idx = rep * 256 + tid;
            int r = idx >> 6, cq = idx & 63;
            At[r][cq] = yw[(size_t)(i0 + r) * 256 + j0 + cq];          // At[contract][i_out]
            Bt[cq][r] = src[(size_t)(n0 + r) * 1024 + d * 256 + i0 + cq]; // Bt[contract][n]
        }
        __syncthreads();
        for (int ii = 0; ii < 64; ++ii) {
            float4 a4 = *(const float4*)(&At[ii][ty * 4]);
            float4 b4 = *(const float4*)(&Bt[ii][tx * 4]);
            float av[4] = {a4.x, a4.y, a4.z, a4.w};
            float bv[4] = {b4.x, b4.y, b4.z, b4.w};
            for (int q = 0; q < 4; ++q)
                for (int p = 0; p < 4; ++p)
                    acc[q][p] = fmaf(av[q], bv[p], acc[q][p]);
        }
        __syncthreads();
    }
    for (int q = 0; q < 4; ++q) {
        int k = d * 256 + j0 + ty * 4 + q;   // folded K index
        for (int p = 0; p < 4; ++p) {
            int n = n0 + tx * 4 + p;
            WBT[(size_t)(mat * 256 + n) * 1024 + k] = f2b(acc[q][p]);
        }
    }
}

// folded biases: bm2[n] = mb[n] + sum_k mw[n][k]*yb[k%256]
__global__ void k_foldbias(const float* __restrict__ mw, const float* __restrict__ gw,
                           const float* __restrict__ mb, const float* __restrict__ gb,
                           const float* __restrict__ yb,
                           float* __restrict__ bm2, float* __restrict__ bg2)
{
    int t = threadIdx.x;          // 0..511
    int n = t & 255;
    const float* W = (t < 256) ? mw : gw;
    float acc = (t < 256) ? mb[n] : gb[n];
    for (int k = 0; k < 1024; ++k)
        acc = fmaf(W[(size_t)n * 1024 + k], yb[k & 255], acc);
    if (t < 256) bm2[n] = acc; else bg2[n] = acc;
}

// ---------------- transpose x to bf16 two-plane row-major XT[p][192]:
// k 0..95 = bf16_hi(x[ch]), k 96..191 = bf16_lo residual. p = b*LL + l.
__global__ __launch_bounds__(256) void k_xpose(
    const float* __restrict__ x, unsigned short* __restrict__ XT)
{
    int t = threadIdx.x;
    int p0 = blockIdx.x * 256;
    int b = p0 >> 14;
    int l = (p0 & (LL - 1)) + t;
    size_t gp = (size_t)(p0 + t);
    const float* xr = x + (size_t)b * 96 * LL + l;
    unsigned short* orow = XT + gp * 192;
#pragma unroll
    for (int kq = 0; kq < 12; ++kq) {
        short8v hi, lo;
#pragma unroll
        for (int c = 0; c < 8; ++c) {
            float v = xr[(size_t)(kq * 8 + c) * LL];
            unsigned short h = f2b(v);
            float r = v - b2f(h);
            hi[c] = (short)h;
            lo[c] = (short)f2b(r);
        }
        *(short8v*)(orow + kq * 8) = hi;
        *(short8v*)(orow + 96 + kq * 8) = lo;
    }
}

// ---------------- pack in-proj weights bf16 row-major WPT[r'][192], both halves = w_hi:
// r' = nn16*64 + g*16 + ni  (g: 0=xw,1=B,2=C,3=delta; n = nn16*16+ni)
__global__ void k_wprep(
    const float* __restrict__ xw, const float* __restrict__ bcw, const float* __restrict__ dw,
    unsigned short* __restrict__ WPT)
{
    int rp = blockIdx.x * 256 + threadIdx.x;   // 0..1023
    int nn16 = rp >> 6, g = (rp >> 4) & 3, ni = rp & 15;
    int n = nn16 * 16 + ni;
    const float* row;
    if (g == 0)      row = xw + (size_t)n * 96;
    else if (g == 1) row = bcw + (size_t)n * 96;
    else if (g == 2) row = bcw + (size_t)(256 + n) * 96;
    else             row = dw + (size_t)n * 96;
    unsigned short* orow = WPT + (size_t)rp * 192;
#pragma unroll
    for (int kq = 0; kq < 12; ++kq) {
        short8v hv;
#pragma unroll
        for (int c = 0; c < 8; ++c) hv[c] = (short)f2b(row[kq * 8 + c]);
        *(short8v*)(orow + kq * 8) = hv;
        *(short8v*)(orow + 96 + kq * 8) = hv;
    }
}

// ---------------- in-projection via MFMA (k_merge_mfma clone, K=192):
// A = XT[p][192], B = WPT[r'][192]. dot = (x_hi+x_lo)@w_hi = f32-grade x, bf16 w.
// Block: 128 positions x 128 r'. BK=32, 6 K-steps, 2 barriers/step.
__global__ __launch_bounds__(256) void k_proj_mfma(
    const unsigned short* __restrict__ XT, const unsigned short* __restrict__ WPT,
    const float* __restrict__ xb, const float* __restrict__ bcb, const float* __restrict__ db,
    unsigned int* __restrict__ AB, unsigned short* __restrict__ C)
{
    __shared__ __align__(16) unsigned short smA[128 * 32];   // [row][k] bf16, 8 KB
    __shared__ __align__(16) unsigned short smB[128 * 32];   // [r' row][k] bf16, 8 KB
    int tid = threadIdx.x;
    int w = tid >> 6, l = tid & 63;
    int mt = blockIdx.x;          // 256 row tiles of 128 positions
    int bnt = blockIdx.y;         // 8 r' tiles of 128
    int p0 = mt * 128;
    int bn0 = bnt * 128;

    int rowA = tid >> 2;          // 0..63
    int chA  = tid & 3;
    int laneRow = l & 15;
    int laneK   = l >> 4;

    float4v acc[2][8];
#pragma unroll
    for (int i = 0; i < 2; ++i)
#pragma unroll
        for (int f = 0; f < 8; ++f) acc[i][f] = (float4v)0.f;

    for (int kt = 0; kt < 6; ++kt) {
        const unsigned short* gA = XT + (size_t)(p0 + rowA) * 192 + kt * 32 + chA * 8;
        const unsigned short* gB = WPT + (size_t)(bn0 + rowA) * 192 + kt * 32 + chA * 8;
        GLL16(gA,            smA + tid * 8);
        GLL16(gA + 64 * 192, smA + 2048 + tid * 8);
        GLL16(gB,            smB + tid * 8);
        GLL16(gB + 64 * 192, smB + 2048 + tid * 8);
        __syncthreads();

        short8v a0 = *(const short8v*)(&smA[(w * 32 + laneRow) * 32 + laneK * 8]);
        short8v a1 = *(const short8v*)(&smA[(w * 32 + 16 + laneRow) * 32 + laneK * 8]);
#pragma unroll
        for (int f = 0; f < 8; ++f) {
            short8v bf_ = *(const short8v*)(&smB[(f * 16 + laneRow) * 32 + laneK * 8]);
            acc[0][f] = __builtin_amdgcn_mfma_f32_16x16x32_bf16(a0, bf_, acc[0][f], 0, 0, 0);
            acc[1][f] = __builtin_amdgcn_mfma_f32_16x16x32_bf16(a1, bf_, acc[1][f], 0, 0, 0);
        }
        __syncthreads();
    }

    int lr = l >> 4, lc = l & 15;
#pragma unroll
    for (int mr = 0; mr < 2; ++mr) {
#pragma unroll
        for (int nn2 = 0; nn2 < 2; ++nn2) {
            int n = (bnt * 2 + nn2) * 16 + lc;
            float xbv = xb[n], bb = bcb[n], cb = bcb[256 + n], dbv = db[n];
#pragma unroll
            for (int q = 0; q < 4; ++q) {
                int p = p0 + w * 32 + mr * 16 + lr * 4 + q;
                float u  = acc[mr][nn2 * 4 + 0][q] + xbv;
                float Bm = acc[mr][nn2 * 4 + 1][q] + bb;
                float Cm = acc[mr][nn2 * 4 + 2][q] + cb;
                float dl = acc[mr][nn2 * 4 + 3][q] + dbv;
                float a  = 1.0f / (1.0f + __expf(dl));   // exp(-softplus(d)) == sigmoid(-d)
                float bu = (1.0f - a) * Bm * u;
                size_t base = (size_t)p * NLAT + n;      // p == b*LL + l
                AB[base] = (unsigned int)f2b(a) | ((unsigned int)f2b(bu) << 16);
                C[base]  = f2b(Cm);
            }
        }
    }
}

__device__ __forceinline__ int src_pos(int d, int t) {
    int s = (d >= 2) ? (LL - 1 - t) : t;
    return (d & 1) ? (((s & 127) << 7) | (s >> 7)) : s;   // dirs 1,3 traverse transposed order
}

// ---------------- scan pass 1: per-chunk aggregates (A_prod, B_acc)
__global__ __launch_bounds__(256) void k_scan1(
    const unsigned int* __restrict__ AB,
    float* __restrict__ AggA, float* __restrict__ AggB)
{
    int n = threadIdx.x;
    int c = blockIdx.x, d = blockIdx.y, b = blockIdx.z;
    float h = 0.f, Ap = 1.f;
    int t0 = c * 256;
#pragma unroll 4
    for (int i = 0; i < 256; ++i) {
        int ls = src_pos(d, t0 + i);
        unsigned int v = AB[((size_t)b * LL + ls) * NLAT + n];
        float a  = __uint_as_float(v << 16);
        float bu = __uint_as_float(v & 0xFFFF0000u);
        h = fmaf(a, h, bu);
        Ap *= a;
    }
    size_t o = (((size_t)b * 4 + d) * 64 + c) * NLAT + n;
    AggA[o] = Ap; AggB[o] = h;
}

// ---------------- scan pass 2: serial scan over 64 chunk aggregates
__global__ void k_scan2(const float* __restrict__ AggA, const float* __restrict__ AggB,
                        float* __restrict__ Hs)
{
    int n = threadIdx.x;
    int d = blockIdx.x, b = blockIdx.y;
    float h = 0.f;
    for (int c = 0; c < 64; ++c) {
        size_t o = (((size_t)b * 4 + d) * 64 + c) * NLAT + n;
        Hs[o] = h;
        h = fmaf(AggA[o], h, AggB[o]);
    }
}

// ---------------- scan pass 3: replay with true h_in, y = C*h
__global__ __launch_bounds__(256) void k_scan3(
    const unsigned int* __restrict__ AB, const unsigned short* __restrict__ C,
    const float* __restrict__ Hs, unsigned short* __restrict__ ys)
{
    int n = threadIdx.x;
    int c = blockIdx.x, d = blockIdx.y, b = blockIdx.z;
    size_t o = (((size_t)b * 4 + d) * 64 + c) * NLAT + n;
    float h = Hs[o];
    int t0 = c * 256;
    size_t ybase = (((size_t)b * 4 + d) * LL + t0) * NLAT + n;
#pragma unroll 4
    for (int i = 0; i < 256; ++i) {
        int ls = src_pos(d, t0 + i);
        size_t idx = ((size_t)b * LL + ls) * NLAT + n;
        unsigned int v = AB[idx];
        float a  = __uint_as_float(v << 16);
        float bu = __uint_as_float(v & 0xFFFF0000u);
        h = fmaf(a, h, bu);
        float y = b2f(C[idx]) * h;
        ys[ybase + (size_t)i * NLAT] = f2b(y);
    }
}

// ---------------- merge (MFMA bf16): z = (ys_cat@WM + bm2) * sigmoid(ys_cat@WG + bg2)
__global__ __launch_bounds__(256) void k_merge_mfma(
    const unsigned short* __restrict__ ys,
    const unsigned short* __restrict__ WBT,
    const float* __restrict__ bm2, const float* __restrict__ bg2,
    unsigned short* __restrict__ z)
{
    __shared__ __align__(16) unsigned short smA[128 * 32];   // [row][k] bf16, 8 KB
    __shared__ __align__(16) unsigned short smB[128 * 32];   // [colInTile][k] bf16, 8 KB
    int tid = threadIdx.x;
    int w = tid >> 6, l = tid & 63;
    int mt = blockIdx.x;          // 0..255 row tiles
    int nt = blockIdx.y;          // 0..3 n tiles of 64
    int p0 = mt * 128;
    int b4 = (p0 >> 14) * 4;
    int l0 = p0 & (LL - 1);
    int n0 = nt * 64;

    int rowA = tid >> 2;          // 0..63
    int chA  = tid & 3;
    int laneRow = l & 15;
    int laneK   = l >> 4;

    float4v accM[2][4], accG[2][4];
#pragma unroll
    for (int i = 0; i < 2; ++i)
#pragma unroll
        for (int j = 0; j < 4; ++j) { accM[i][j] = (float4v)0.f; accG[i][j] = (float4v)0.f; }

    for (int kt = 0; kt < 32; ++kt) {
        int d = kt >> 3;
        int j0k = (kt & 7) * 32;
        const unsigned short* gA = ys + (((size_t)(b4 + d)) * LL + l0 + rowA) * 256 + j0k + chA * 8;
        const unsigned short* gB = WBT + ((size_t)(n0 + rowA)) * 1024 + kt * 32 + chA * 8;
        GLL16(gA,              smA + tid * 8);
        GLL16(gA + 64 * 256,   smA + 2048 + tid * 8);
        GLL16(gB,              smB + tid * 8);
        GLL16(gB + 256 * 1024, smB + 2048 + tid * 8);
        __syncthreads();

        short8v a0 = *(const short8v*)(&smA[(w * 32 + laneRow) * 32 + laneK * 8]);
        short8v a1 = *(const short8v*)(&smA[(w * 32 + 16 + laneRow) * 32 + laneK * 8]);
#pragma unroll
        for (int nr = 0; nr < 4; ++nr) {
            short8v bm_ = *(const short8v*)(&smB[(nr * 16 + laneRow) * 32 + laneK * 8]);
            short8v bg_ = *(const short8v*)(&smB[(64 + nr * 16 + laneRow) * 32 + laneK * 8]);
            accM[0][nr] = __builtin_amdgcn_mfma_f32_16x16x32_bf16(a0, bm_, accM[0][nr], 0, 0, 0);
            accM[1][nr] = __builtin_amdgcn_mfma_f32_16x16x32_bf16(a1, bm_, accM[1][nr], 0, 0, 0);
            accG[0][nr] = __builtin_amdgcn_mfma_f32_16x16x32_bf16(a0, bg_, accG[0][nr], 0, 0, 0);
            accG[1][nr] = __builtin_amdgcn_mfma_f32_16x16x32_bf16(a1, bg_, accG[1][nr], 0, 0, 0);
        }
        __syncthreads();
    }

    int lr = l >> 4, lc = l & 15;
#pragma unroll
    for (int mr = 0; mr < 2; ++mr) {
#pragma unroll
        for (int nr = 0; nr < 4; ++nr) {
            int n = n0 + nr * 16 + lc;
            float bmv = bm2[n], bgv = bg2[n];
#pragma unroll
            for (int q = 0; q < 4; ++q) {
                int p = p0 + w * 32 + mr * 16 + lr * 4 + q;
                float m = accM[mr][nr][q] + bmv;
                float g = accG[mr][nr][q] + bgv;
                float zv = m / (1.f + __expf(-g));
                z[(size_t)p * NLAT + n] = f2b(zv);
            }
        }
    }
}

// ---------------- out projection: out[b][c][l] = z@ow.T + ob  (FLOAT32 out)
__global__ __launch_bounds__(256) void k_out(
    const unsigned short* __restrict__ z,
    const float* __restrict__ ow, const float* __restrict__ ob,
    float* __restrict__ out)
{
    __shared__ float Zt[64][68];
    __shared__ float Wt[64][100];
    int tid = threadIdx.x;
    int p0 = blockIdx.x * 64;
    int tx = tid & 15, ty = tid >> 4;
    float acc[4][6] = {};
    for (int kt = 0; kt < 4; ++kt) {
        int k0 = kt * 64;
        for (int rep = 0; rep < 16; ++rep) {
            int idx = rep * 256 + tid;
            int r = idx >> 6, kk = idx & 63;
            Zt[kk][r] = b2f(z[(size_t)(p0 + r) * NLAT + k0 + kk]);
        }
        for (int rep = 0; rep < 24; ++rep) {
            int idx = rep * 256 + tid;
            int cc = idx >> 6;      // 0..95
            int kk = idx & 63;
            Wt[kk][cc] = ow[(size_t)cc * NLAT + k0 + kk];
        }
        __syncthreads();
        for (int kk = 0; kk < 64; ++kk) {
            float zv[4];
            for (int rr = 0; rr < 4; ++rr) zv[rr] = Zt[kk][tx + 16 * rr];
            for (int m = 0; m < 6; ++m) {
                float wv = Wt[kk][ty + 16 * m];
                for (int rr = 0; rr < 4; ++rr) acc[rr][m] = fmaf(zv[rr], wv, acc[rr][m]);
            }
        }
        __syncthreads();
    }
    for (int m = 0; m < 6; ++m) {
        int cch = ty + 16 * m;
        float obv = ob[cch];
        for (int rr = 0; rr < 4; ++rr) {
            int p = p0 + tx + 16 * rr;
            int b = p >> 14, l = p & (LL - 1);
            out[((size_t)b * 96 + cch) * LL + l] = acc[rr][m] + obv;
        }
    }
}

extern "C" void kernel_launch(void* const* d_in, const int* in_sizes, int n_in,
                              void* d_out, int out_size, void* d_ws, size_t ws_size,
                              hipStream_t stream) {
    (void)in_sizes; (void)n_in; (void)out_size; (void)ws_size;
    const float* x   = (const float*)d_in[0];
    const float* xw  = (const float*)d_in[1];
    const float* xb  = (const float*)d_in[2];
    const float* bcw = (const float*)d_in[3];
    const float* bcb = (const float*)d_in[4];
    const float* dw  = (const float*)d_in[5];
    const float* db  = (const float*)d_in[6];
    const float* yw  = (const float*)d_in[7];
    const float* yb  = (const float*)d_in[8];
    const float* mw  = (const float*)d_in[9];
    const float* mb  = (const float*)d_in[10];
    const float* gw  = (const float*)d_in[11];
    const float* gb  = (const float*)d_in[12];
    const float* ow  = (const float*)d_in[13];
    const float* ob  = (const float*)d_in[14];
    float* out = (float*)d_out;

    char* ws = (char*)d_ws;
    size_t off = 0;
    auto alloc = [&](size_t bytes) -> void* {
        void* p = ws + off;
        off += (bytes + 255) & ~(size_t)255;
        return p;
    };
    unsigned int*   AB  = (unsigned int*)  alloc((size_t)NB * LL * NLAT * 4);     // 33.6 MB
    unsigned short* C   = (unsigned short*)alloc((size_t)NB * LL * NLAT * 2);     // 16.8 MB
    unsigned short* YS  = (unsigned short*)alloc((size_t)NB * 4 * LL * NLAT * 2); // 67 MB
    unsigned short* Z   = (unsigned short*)alloc((size_t)NB * LL * NLAT * 2);     // 16.8 MB
    unsigned short* WBT = (unsigned short*)alloc((size_t)512 * 1024 * 2);         // 1 MB
    unsigned short* XT  = (unsigned short*)alloc((size_t)NB * LL * 192 * 2);      // 12.6 MB
    unsigned short* WPT = (unsigned short*)alloc((size_t)1024 * 192 * 2);         // 0.39 MB
    float* BM2  = (float*)alloc(256 * 4);
    float* BG2  = (float*)alloc(256 * 4);
    float* AggA = (float*)alloc((size_t)NB * 4 * 64 * NLAT * 4);
    float* AggB = (float*)alloc((size_t)NB * 4 * 64 * NLAT * 4);
    float* HS   = (float*)alloc((size_t)NB * 4 * 64 * NLAT * 4);

    k_foldw     <<<dim3(4, 4, 8),   256, 0, stream>>>(yw, mw, gw, WBT);
    k_foldbias  <<<1,               512, 0, stream>>>(mw, gw, mb, gb, yb, BM2, BG2);
    k_wprep     <<<4,               256, 0, stream>>>(xw, bcw, dw, WPT);
    k_xpose     <<<128,             256, 0, stream>>>(x, XT);
    k_proj_mfma <<<dim3(256, 8),    256, 0, stream>>>(XT, WPT, xb, bcb, db, AB, C);
    k_scan1     <<<dim3(64, 4, NB), 256, 0, stream>>>(AB, AggA, AggB);
    k_scan2     <<<dim3(4, NB),     256, 0, stream>>>(AggA, AggB, HS);
    k_scan3     <<<dim3(64, 4, NB), 256, 0, stream>>>(AB, C, HS, YS);
    k_merge_mfma<<<dim3(256, 4),    256, 0, stream>>>(YS, WBT, BM2, BG2, Z);
    k_out       <<<512,             256, 0, stream>>>(Z, ow, ob, out);
}

// Round 6
// 302.480 us; speedup vs baseline: 2.7747x; 1.1672x over previous
//
#include <hip/hip_runtime.h>
#include <stdint.h>

#define LL 16384
#define NB 2
#define CIN 96
#define NLAT 256
#define COUT 96

typedef __attribute__((ext_vector_type(8))) short short8v;
typedef __attribute__((ext_vector_type(4))) float float4v;

__device__ __forceinline__ float b2f(unsigned short h) {
    return __uint_as_float(((unsigned int)h) << 16);
}
__device__ __forceinline__ unsigned short f2b(float f) {
    unsigned int u = __float_as_uint(f);
    unsigned int r = (u + 0x7FFFu + ((u >> 16) & 1u)) >> 16;
    return (unsigned short)r;
}

#define GLL16(g, s) __builtin_amdgcn_global_load_lds( \
    (const __attribute__((address_space(1))) unsigned int*)(g), \
    (__attribute__((address_space(3))) unsigned int*)(s), 16, 0, 0)

// ---------------- fold weights into bf16 transposed WBT[n'][k]:
//   n' = mat*256 + n (mat 0 = merge, 1 = gate), k = d*256 + i
//   WBT[n'][k] = sum_j yw[j][i] * (mat?gw:mw)[n][d*256+j]
__global__ __launch_bounds__(256) void k_foldw(
    const float* __restrict__ yw, const float* __restrict__ mw, const float* __restrict__ gw,
    unsigned short* __restrict__ WBT)
{
    __shared__ float At[64][68];
    __shared__ float Bt[64][68];
    int jt = blockIdx.x, nt = blockIdx.y, dz = blockIdx.z;
    int d = dz & 3, mat = dz >> 2;
    const float* src = mat ? gw : mw;
    int j0 = jt * 64, n0 = nt * 64;
    int tid = threadIdx.x, tx = tid & 15, ty = tid >> 4;
    float acc[4][4] = {};
    for (int kt = 0; kt < 4; ++kt) {
        int i0 = kt * 64;
        for (int rep = 0; rep < 16; ++rep) {
            int idx = rep * 256 + tid;
            int r = idx >> 6, cq = idx & 63;
            At[r][cq] = yw[(size_t)(i0 + r) * 256 + j0 + cq];          // At[contract][i_out]
            Bt[cq][r] = src[(size_t)(n0 + r) * 1024 + d * 256 + i0 + cq]; // Bt[contract][n]
        }
        __syncthreads();
        for (int ii = 0; ii < 64; ++ii) {
            float4 a4 = *(const float4*)(&At[ii][ty * 4]);
            float4 b4 = *(const float4*)(&Bt[ii][tx * 4]);
            float av[4] = {a4.x, a4.y, a4.z, a4.w};
            float bv[4] = {b4.x, b4.y, b4.z, b4.w};
            for (int q = 0; q < 4; ++q)
                for (int p = 0; p < 4; ++p)
                    acc[q][p] = fmaf(av[q], bv[p], acc[q][p]);
        }
        __syncthreads();
    }
    for (int q = 0; q < 4; ++q) {
        int k = d * 256 + j0 + ty * 4 + q;   // folded K index
        for (int p = 0; p < 4; ++p) {
            int n = n0 + tx * 4 + p;
            WBT[(size_t)(mat * 256 + n) * 1024 + k] = f2b(acc[q][p]);
        }
    }
}

// folded biases: bm2[n] = mb[n] + sum_k mw[n][k]*yb[k%256]
__global__ void k_foldbias(const float* __restrict__ mw, const float* __restrict__ gw,
                           const float* __restrict__ mb, const float* __restrict__ gb,
                           const float* __restrict__ yb,
                           float* __restrict__ bm2, float* __restrict__ bg2)
{
    int t = threadIdx.x;          // 0..511
    int n = t & 255;
    const float* W = (t < 256) ? mw : gw;
    float acc = (t < 256) ? mb[n] : gb[n];
    for (int k = 0; k < 1024; ++k)
        acc = fmaf(W[(size_t)n * 1024 + k], yb[k & 255], acc);
    if (t < 256) bm2[n] = acc; else bg2[n] = acc;
}

// ---------------- transpose x to bf16 two-plane row-major XT[p][192]:
// k 0..95 = bf16_hi(x[ch]), k 96..191 = bf16_lo residual. p = b*LL + l.
__global__ __launch_bounds__(256) void k_xpose(
    const float* __restrict__ x, unsigned short* __restrict__ XT)
{
    int t = threadIdx.x;
    int p0 = blockIdx.x * 256;
    int b = p0 >> 14;
    int l = (p0 & (LL - 1)) + t;
    size_t gp = (size_t)(p0 + t);
    const float* xr = x + (size_t)b * 96 * LL + l;
    unsigned short* orow = XT + gp * 192;
#pragma unroll
    for (int kq = 0; kq < 12; ++kq) {
        short8v hi, lo;
#pragma unroll
        for (int c = 0; c < 8; ++c) {
            float v = xr[(size_t)(kq * 8 + c) * LL];
            unsigned short h = f2b(v);
            float r = v - b2f(h);
            hi[c] = (short)h;
            lo[c] = (short)f2b(r);
        }
        *(short8v*)(orow + kq * 8) = hi;
        *(short8v*)(orow + 96 + kq * 8) = lo;
    }
}

// ---------------- pack in-proj weights bf16 row-major WPT[r'][192], both halves = w_hi:
// r' = nn16*64 + g*16 + ni  (g: 0=xw,1=B,2=C,3=delta; n = nn16*16+ni)
__global__ void k_wprep(
    const float* __restrict__ xw, const float* __restrict__ bcw, const float* __restrict__ dw,
    unsigned short* __restrict__ WPT)
{
    int rp = blockIdx.x * 256 + threadIdx.x;   // 0..1023
    int nn16 = rp >> 6, g = (rp >> 4) & 3, ni = rp & 15;
    int n = nn16 * 16 + ni;
    const float* row;
    if (g == 0)      row = xw + (size_t)n * 96;
    else if (g == 1) row = bcw + (size_t)n * 96;
    else if (g == 2) row = bcw + (size_t)(256 + n) * 96;
    else             row = dw + (size_t)n * 96;
    unsigned short* orow = WPT + (size_t)rp * 192;
#pragma unroll
    for (int kq = 0; kq < 12; ++kq) {
        short8v hv;
#pragma unroll
        for (int c = 0; c < 8; ++c) hv[c] = (short)f2b(row[kq * 8 + c]);
        *(short8v*)(orow + kq * 8) = hv;
        *(short8v*)(orow + 96 + kq * 8) = hv;
    }
}

// ---------------- pack out-proj weights bf16 OWB[128][256] (rows 96..127 zero)
__global__ void k_owprep(const float* __restrict__ ow, unsigned short* __restrict__ OWB)
{
    int t = threadIdx.x;          // 256
    int r = t >> 1, h = t & 1;
    unsigned short* orow = OWB + (size_t)r * 256 + h * 128;
    const float* src = ow + (size_t)r * 256 + h * 128;
#pragma unroll
    for (int c8 = 0; c8 < 16; ++c8) {
        short8v v;
        if (r < 96) {
#pragma unroll
            for (int c = 0; c < 8; ++c) v[c] = (short)f2b(src[c8 * 8 + c]);
        } else {
#pragma unroll
            for (int c = 0; c < 8; ++c) v[c] = 0;
        }
        *(short8v*)(orow + c8 * 8) = v;
    }
}

// ---------------- in-projection via MFMA (k_merge_mfma clone, K=192):
// A = XT[p][192], B = WPT[r'][192]. dot = (x_hi+x_lo)@w_hi = f32-grade x, bf16 w.
// Block: 128 positions x 128 r'. BK=32, 6 K-steps, 2 barriers/step.
__global__ __launch_bounds__(256) void k_proj_mfma(
    const unsigned short* __restrict__ XT, const unsigned short* __restrict__ WPT,
    const float* __restrict__ xb, const float* __restrict__ bcb, const float* __restrict__ db,
    unsigned int* __restrict__ AB, unsigned short* __restrict__ C)
{
    __shared__ __align__(16) unsigned short smA[128 * 32];   // [row][k] bf16, 8 KB
    __shared__ __align__(16) unsigned short smB[128 * 32];   // [r' row][k] bf16, 8 KB
    int tid = threadIdx.x;
    int w = tid >> 6, l = tid & 63;
    int mt = blockIdx.x;          // 256 row tiles of 128 positions
    int bnt = blockIdx.y;         // 8 r' tiles of 128
    int p0 = mt * 128;
    int bn0 = bnt * 128;

    int rowA = tid >> 2;          // 0..63
    int chA  = tid & 3;
    int laneRow = l & 15;
    int laneK   = l >> 4;

    float4v acc[2][8];
#pragma unroll
    for (int i = 0; i < 2; ++i)
#pragma unroll
        for (int f = 0; f < 8; ++f) acc[i][f] = (float4v)0.f;

    for (int kt = 0; kt < 6; ++kt) {
        const unsigned short* gA = XT + (size_t)(p0 + rowA) * 192 + kt * 32 + chA * 8;
        const unsigned short* gB = WPT + (size_t)(bn0 + rowA) * 192 + kt * 32 + chA * 8;
        GLL16(gA,            smA + tid * 8);
        GLL16(gA + 64 * 192, smA + 2048 + tid * 8);
        GLL16(gB,            smB + tid * 8);
        GLL16(gB + 64 * 192, smB + 2048 + tid * 8);
        __syncthreads();

        short8v a0 = *(const short8v*)(&smA[(w * 32 + laneRow) * 32 + laneK * 8]);
        short8v a1 = *(const short8v*)(&smA[(w * 32 + 16 + laneRow) * 32 + laneK * 8]);
#pragma unroll
        for (int f = 0; f < 8; ++f) {
            short8v bf_ = *(const short8v*)(&smB[(f * 16 + laneRow) * 32 + laneK * 8]);
            acc[0][f] = __builtin_amdgcn_mfma_f32_16x16x32_bf16(a0, bf_, acc[0][f], 0, 0, 0);
            acc[1][f] = __builtin_amdgcn_mfma_f32_16x16x32_bf16(a1, bf_, acc[1][f], 0, 0, 0);
        }
        __syncthreads();
    }

    int lr = l >> 4, lc = l & 15;
#pragma unroll
    for (int mr = 0; mr < 2; ++mr) {
#pragma unroll
        for (int nn2 = 0; nn2 < 2; ++nn2) {
            int n = (bnt * 2 + nn2) * 16 + lc;
            float xbv = xb[n], bb = bcb[n], cb = bcb[256 + n], dbv = db[n];
#pragma unroll
            for (int q = 0; q < 4; ++q) {
                int p = p0 + w * 32 + mr * 16 + lr * 4 + q;
                float u  = acc[mr][nn2 * 4 + 0][q] + xbv;
                float Bm = acc[mr][nn2 * 4 + 1][q] + bb;
                float Cm = acc[mr][nn2 * 4 + 2][q] + cb;
                float dl = acc[mr][nn2 * 4 + 3][q] + dbv;
                float a  = 1.0f / (1.0f + __expf(dl));   // exp(-softplus(d)) == sigmoid(-d)
                float bu = (1.0f - a) * Bm * u;
                size_t base = (size_t)p * NLAT + n;      // p == b*LL + l
                AB[base] = (unsigned int)f2b(a) | ((unsigned int)f2b(bu) << 16);
                C[base]  = f2b(Cm);
            }
        }
    }
}

__device__ __forceinline__ int src_pos(int d, int t) {
    int s = (d >= 2) ? (LL - 1 - t) : t;
    return (d & 1) ? (((s & 127) << 7) | (s >> 7)) : s;   // dirs 1,3 traverse transposed order
}

// ---------------- scan pass 1: per-chunk aggregates (A_prod, B_acc)
__global__ __launch_bounds__(256) void k_scan1(
    const unsigned int* __restrict__ AB,
    float* __restrict__ AggA, float* __restrict__ AggB)
{
    int n = threadIdx.x;
    int c = blockIdx.x, d = blockIdx.y, b = blockIdx.z;
    float h = 0.f, Ap = 1.f;
    int t0 = c * 256;
#pragma unroll 4
    for (int i = 0; i < 256; ++i) {
        int ls = src_pos(d, t0 + i);
        unsigned int v = AB[((size_t)b * LL + ls) * NLAT + n];
        float a  = __uint_as_float(v << 16);
        float bu = __uint_as_float(v & 0xFFFF0000u);
        h = fmaf(a, h, bu);
        Ap *= a;
    }
    size_t o = (((size_t)b * 4 + d) * 64 + c) * NLAT + n;
    AggA[o] = Ap; AggB[o] = h;
}

// ---------------- scan pass 2: serial scan over 64 chunk aggregates
__global__ void k_scan2(const float* __restrict__ AggA, const float* __restrict__ AggB,
                        float* __restrict__ Hs)
{
    int n = threadIdx.x;
    int d = blockIdx.x, b = blockIdx.y;
    float h = 0.f;
    for (int c = 0; c < 64; ++c) {
        size_t o = (((size_t)b * 4 + d) * 64 + c) * NLAT + n;
        Hs[o] = h;
        h = fmaf(AggA[o], h, AggB[o]);
    }
}

// ---------------- scan pass 3: replay with true h_in, y = C*h
__global__ __launch_bounds__(256) void k_scan3(
    const unsigned int* __restrict__ AB, const unsigned short* __restrict__ C,
    const float* __restrict__ Hs, unsigned short* __restrict__ ys)
{
    int n = threadIdx.x;
    int c = blockIdx.x, d = blockIdx.y, b = blockIdx.z;
    size_t o = (((size_t)b * 4 + d) * 64 + c) * NLAT + n;
    float h = Hs[o];
    int t0 = c * 256;
    size_t ybase = (((size_t)b * 4 + d) * LL + t0) * NLAT + n;
#pragma unroll 4
    for (int i = 0; i < 256; ++i) {
        int ls = src_pos(d, t0 + i);
        size_t idx = ((size_t)b * LL + ls) * NLAT + n;
        unsigned int v = AB[idx];
        float a  = __uint_as_float(v << 16);
        float bu = __uint_as_float(v & 0xFFFF0000u);
        h = fmaf(a, h, bu);
        float y = b2f(C[idx]) * h;
        ys[ybase + (size_t)i * NLAT] = f2b(y);
    }
}

// ---------------- merge (MFMA bf16): z = (ys_cat@WM + bm2) * sigmoid(ys_cat@WG + bg2)
__global__ __launch_bounds__(256) void k_merge_mfma(
    const unsigned short* __restrict__ ys,
    const unsigned short* __restrict__ WBT,
    const float* __restrict__ bm2, const float* __restrict__ bg2,
    unsigned short* __restrict__ z)
{
    __shared__ __align__(16) unsigned short smA[128 * 32];   // [row][k] bf16, 8 KB
    __shared__ __align__(16) unsigned short smB[128 * 32];   // [colInTile][k] bf16, 8 KB
    int tid = threadIdx.x;
    int w = tid >> 6, l = tid & 63;
    int mt = blockIdx.x;          // 0..255 row tiles
    int nt = blockIdx.y;          // 0..3 n tiles of 64
    int p0 = mt * 128;
    int b4 = (p0 >> 14) * 4;
    int l0 = p0 & (LL - 1);
    int n0 = nt * 64;

    int rowA = tid >> 2;          // 0..63
    int chA  = tid & 3;
    int laneRow = l & 15;
    int laneK   = l >> 4;

    float4v accM[2][4], accG[2][4];
#pragma unroll
    for (int i = 0; i < 2; ++i)
#pragma unroll
        for (int j = 0; j < 4; ++j) { accM[i][j] = (float4v)0.f; accG[i][j] = (float4v)0.f; }

    for (int kt = 0; kt < 32; ++kt) {
        int d = kt >> 3;
        int j0k = (kt & 7) * 32;
        const unsigned short* gA = ys + (((size_t)(b4 + d)) * LL + l0 + rowA) * 256 + j0k + chA * 8;
        const unsigned short* gB = WBT + ((size_t)(n0 + rowA)) * 1024 + kt * 32 + chA * 8;
        GLL16(gA,              smA + tid * 8);
        GLL16(gA + 64 * 256,   smA + 2048 + tid * 8);
        GLL16(gB,              smB + tid * 8);
        GLL16(gB + 256 * 1024, smB + 2048 + tid * 8);
        __syncthreads();

        short8v a0 = *(const short8v*)(&smA[(w * 32 + laneRow) * 32 + laneK * 8]);
        short8v a1 = *(const short8v*)(&smA[(w * 32 + 16 + laneRow) * 32 + laneK * 8]);
#pragma unroll
        for (int nr = 0; nr < 4; ++nr) {
            short8v bm_ = *(const short8v*)(&smB[(nr * 16 + laneRow) * 32 + laneK * 8]);
            short8v bg_ = *(const short8v*)(&smB[(64 + nr * 16 + laneRow) * 32 + laneK * 8]);
            accM[0][nr] = __builtin_amdgcn_mfma_f32_16x16x32_bf16(a0, bm_, accM[0][nr], 0, 0, 0);
            accM[1][nr] = __builtin_amdgcn_mfma_f32_16x16x32_bf16(a1, bm_, accM[1][nr], 0, 0, 0);
            accG[0][nr] = __builtin_amdgcn_mfma_f32_16x16x32_bf16(a0, bg_, accG[0][nr], 0, 0, 0);
            accG[1][nr] = __builtin_amdgcn_mfma_f32_16x16x32_bf16(a1, bg_, accG[1][nr], 0, 0, 0);
        }
        __syncthreads();
    }

    int lr = l >> 4, lc = l & 15;
#pragma unroll
    for (int mr = 0; mr < 2; ++mr) {
#pragma unroll
        for (int nr = 0; nr < 4; ++nr) {
            int n = n0 + nr * 16 + lc;
            float bmv = bm2[n], bgv = bg2[n];
#pragma unroll
            for (int q = 0; q < 4; ++q) {
                int p = p0 + w * 32 + mr * 16 + lr * 4 + q;
                float m = accM[mr][nr][q] + bmv;
                float g = accG[mr][nr][q] + bgv;
                float zv = m / (1.f + __expf(-g));
                z[(size_t)p * NLAT + n] = f2b(zv);
            }
        }
    }
}

// ---------------- out projection via MFMA (k_merge_mfma clone, K=256):
// A = Z[p][256] bf16, B = OWB[c][256] bf16 (128 rows, 96 real).
// Block: 128 positions x 96 channels. out[(b*96+c)*LL + l] f32.
__global__ __launch_bounds__(256) void k_out_mfma(
    const unsigned short* __restrict__ z, const unsigned short* __restrict__ OWB,
    const float* __restrict__ ob, float* __restrict__ out)
{
    __shared__ __align__(16) unsigned short smA[128 * 32];   // [row][k] bf16, 8 KB
    __shared__ __align__(16) unsigned short smB[128 * 32];   // [ch row][k] bf16, 8 KB
    int tid = threadIdx.x;
    int w = tid >> 6, l = tid & 63;
    int p0 = blockIdx.x * 128;
    int b = p0 >> 14;
    int l0 = p0 & (LL - 1);

    int rowA = tid >> 2;          // 0..63
    int chA  = tid & 3;
    int laneRow = l & 15;
    int laneK   = l >> 4;

    float4v acc[2][6];
#pragma unroll
    for (int i = 0; i < 2; ++i)
#pragma unroll
        for (int f = 0; f < 6; ++f) acc[i][f] = (float4v)0.f;

    for (int kt = 0; kt < 8; ++kt) {
        const unsigned short* gA = z + (size_t)(p0 + rowA) * 256 + kt * 32 + chA * 8;
        const unsigned short* gB = OWB + (size_t)rowA * 256 + kt * 32 + chA * 8;
        GLL16(gA,            smA + tid * 8);
        GLL16(gA + 64 * 256, smA + 2048 + tid * 8);
        GLL16(gB,            smB + tid * 8);
        GLL16(gB + 64 * 256, smB + 2048 + tid * 8);
        __syncthreads();

        short8v a0 = *(const short8v*)(&smA[(w * 32 + laneRow) * 32 + laneK * 8]);
        short8v a1 = *(const short8v*)(&smA[(w * 32 + 16 + laneRow) * 32 + laneK * 8]);
#pragma unroll
        for (int nr = 0; nr < 6; ++nr) {
            short8v bf_ = *(const short8v*)(&smB[(nr * 16 + laneRow) * 32 + laneK * 8]);
            acc[0][nr] = __builtin_amdgcn_mfma_f32_16x16x32_bf16(a0, bf_, acc[0][nr], 0, 0, 0);
            acc[1][nr] = __builtin_amdgcn_mfma_f32_16x16x32_bf16(a1, bf_, acc[1][nr], 0, 0, 0);
        }
        __syncthreads();
    }

    int lr = l >> 4, lc = l & 15;
#pragma unroll
    for (int mr = 0; mr < 2; ++mr) {
#pragma unroll
        for (int nr = 0; nr < 6; ++nr) {
            int c = nr * 16 + lc;
            float obv = ob[c];
            int ll = l0 + w * 32 + mr * 16 + lr * 4;
            float4 v;
            v.x = acc[mr][nr][0] + obv;
            v.y = acc[mr][nr][1] + obv;
            v.z = acc[mr][nr][2] + obv;
            v.w = acc[mr][nr][3] + obv;
            *(float4*)(&out[((size_t)(b * 96 + c)) * LL + ll]) = v;
        }
    }
}

extern "C" void kernel_launch(void* const* d_in, const int* in_sizes, int n_in,
                              void* d_out, int out_size, void* d_ws, size_t ws_size,
                              hipStream_t stream) {
    (void)in_sizes; (void)n_in; (void)out_size; (void)ws_size;
    const float* x   = (const float*)d_in[0];
    const float* xw  = (const float*)d_in[1];
    const float* xb  = (const float*)d_in[2];
    const float* bcw = (const float*)d_in[3];
    const float* bcb = (const float*)d_in[4];
    const float* dw  = (const float*)d_in[5];
    const float* db  = (const float*)d_in[6];
    const float* yw  = (const float*)d_in[7];
    const float* yb  = (const float*)d_in[8];
    const float* mw  = (const float*)d_in[9];
    const float* mb  = (const float*)d_in[10];
    const float* gw  = (const float*)d_in[11];
    const float* gb  = (const float*)d_in[12];
    const float* ow  = (const float*)d_in[13];
    const float* ob  = (const float*)d_in[14];
    float* out = (float*)d_out;

    char* ws = (char*)d_ws;
    size_t off = 0;
    auto alloc = [&](size_t bytes) -> void* {
        void* p = ws + off;
        off += (bytes + 255) & ~(size_t)255;
        return p;
    };
    unsigned int*   AB  = (unsigned int*)  alloc((size_t)NB * LL * NLAT * 4);     // 33.6 MB
    unsigned short* C   = (unsigned short*)alloc((size_t)NB * LL * NLAT * 2);     // 16.8 MB
    unsigned short* YS  = (unsigned short*)alloc((size_t)NB * 4 * LL * NLAT * 2); // 67 MB
    unsigned short* Z   = (unsigned short*)alloc((size_t)NB * LL * NLAT * 2);     // 16.8 MB
    unsigned short* WBT = (unsigned short*)alloc((size_t)512 * 1024 * 2);         // 1 MB
    unsigned short* XT  = (unsigned short*)alloc((size_t)NB * LL * 192 * 2);      // 12.6 MB
    unsigned short* WPT = (unsigned short*)alloc((size_t)1024 * 192 * 2);         // 0.39 MB
    unsigned short* OWB = (unsigned short*)alloc((size_t)128 * 256 * 2);          // 64 KB
    float* BM2  = (float*)alloc(256 * 4);
    float* BG2  = (float*)alloc(256 * 4);
    float* AggA = (float*)alloc((size_t)NB * 4 * 64 * NLAT * 4);
    float* AggB = (float*)alloc((size_t)NB * 4 * 64 * NLAT * 4);
    float* HS   = (float*)alloc((size_t)NB * 4 * 64 * NLAT * 4);

    k_foldw     <<<dim3(4, 4, 8),   256, 0, stream>>>(yw, mw, gw, WBT);
    k_foldbias  <<<1,               512, 0, stream>>>(mw, gw, mb, gb, yb, BM2, BG2);
    k_wprep     <<<4,               256, 0, stream>>>(xw, bcw, dw, WPT);
    k_owprep    <<<1,               256, 0, stream>>>(ow, OWB);
    k_xpose     <<<128,             256, 0, stream>>>(x, XT);
    k_proj_mfma <<<dim3(256, 8),    256, 0, stream>>>(XT, WPT, xb, bcb, db, AB, C);
    k_scan1     <<<dim3(64, 4, NB), 256, 0, stream>>>(AB, AggA, AggB);
    k_scan2     <<<dim3(4, NB),     256, 0, stream>>>(AggA, AggB, HS);
    k_scan3     <<<dim3(64, 4, NB), 256, 0, stream>>>(AB, C, HS, YS);
    k_merge_mfma<<<dim3(256, 4),    256, 0, stream>>>(YS, WBT, BM2, BG2, Z);
    k_out_mfma  <<<256,             256, 0, stream>>>(Z, OWB, ob, out);
}

// Round 7
// 200.841 us; speedup vs baseline: 4.1789x; 1.5061x over previous
//
#include <hip/hip_runtime.h>
#include <stdint.h>

#define LL 16384
#define NB 2
#define CIN 96
#define NLAT 256
#define COUT 96

typedef __attribute__((ext_vector_type(8))) short short8v;
typedef __attribute__((ext_vector_type(4))) float float4v;

__device__ __forceinline__ float b2f(unsigned short h) {
    return __uint_as_float(((unsigned int)h) << 16);
}
__device__ __forceinline__ unsigned short f2b(float f) {
    unsigned int u = __float_as_uint(f);
    unsigned int r = (u + 0x7FFFu + ((u >> 16) & 1u)) >> 16;
    return (unsigned short)r;
}

#define GLL16(g, s) __builtin_amdgcn_global_load_lds( \
    (const __attribute__((address_space(1))) unsigned int*)(g), \
    (__attribute__((address_space(3))) unsigned int*)(s), 16, 0, 0)

// ---------------- fold weights, split-K partials:
//   out k = d*256 + j (j = output col of yw), n' = mat*256 + n, contraction = 256 rows of yw
//   WF[kc][n'][k] = sum_{i in chunk kc} yw[i][j] * (mat?gw:mw)[n][d*256+i]
__global__ __launch_bounds__(256) void k_foldw_part(
    const float* __restrict__ yw, const float* __restrict__ mw, const float* __restrict__ gw,
    float* __restrict__ WF)
{
    __shared__ float At[64][68];
    __shared__ float Bt[64][68];
    int jt = blockIdx.x, nt = blockIdx.y, dzk = blockIdx.z;
    int kc = dzk & 3, dz = dzk >> 2;
    int d = dz & 3, mat = dz >> 2;
    const float* src = mat ? gw : mw;
    int j0 = jt * 64, n0 = nt * 64;
    int tid = threadIdx.x, tx = tid & 15, ty = tid >> 4;
    float acc[4][4] = {};
    int i0 = kc * 64;
    for (int rep = 0; rep < 16; ++rep) {
        int idx = rep * 256 + tid;
        int r = idx >> 6, cq = idx & 63;
        At[r][cq] = yw[(size_t)(i0 + r) * 256 + j0 + cq];          // At[contract][j_out]
        Bt[cq][r] = src[(size_t)(n0 + r) * 1024 + d * 256 + i0 + cq]; // Bt[contract][n]
    }
    __syncthreads();
    for (int ii = 0; ii < 64; ++ii) {
        float4 a4 = *(const float4*)(&At[ii][ty * 4]);
        float4 b4 = *(const float4*)(&Bt[ii][tx * 4]);
        float av[4] = {a4.x, a4.y, a4.z, a4.w};
        float bv[4] = {b4.x, b4.y, b4.z, b4.w};
        for (int q = 0; q < 4; ++q)
            for (int p = 0; p < 4; ++p)
                acc[q][p] = fmaf(av[q], bv[p], acc[q][p]);
    }
    float* dst = WF + (size_t)kc * 512 * 1024;
    for (int q = 0; q < 4; ++q) {
        int k = d * 256 + j0 + ty * 4 + q;
        for (int p = 0; p < 4; ++p) {
            int n = n0 + tx * 4 + p;
            dst[(size_t)(mat * 256 + n) * 1024 + k] = acc[q][p];
        }
    }
}

// sum the 4 split-K partials, round to bf16
__global__ __launch_bounds__(256) void k_foldsum(
    const float* __restrict__ WF, unsigned short* __restrict__ WBT)
{
    int t = blockIdx.x * 256 + threadIdx.x;    // 131072 threads x 4 elems
    size_t o = (size_t)t * 4;
    const size_t S = (size_t)512 * 1024;
    float4 s0 = *(const float4*)(WF + o);
    float4 s1 = *(const float4*)(WF + S + o);
    float4 s2 = *(const float4*)(WF + 2 * S + o);
    float4 s3 = *(const float4*)(WF + 3 * S + o);
    unsigned short pk[4];
    pk[0] = f2b(s0.x + s1.x + s2.x + s3.x);
    pk[1] = f2b(s0.y + s1.y + s2.y + s3.y);
    pk[2] = f2b(s0.z + s1.z + s2.z + s3.z);
    pk[3] = f2b(s0.w + s1.w + s2.w + s3.w);
    *(unsigned long long*)(&WBT[o]) = *(const unsigned long long*)pk;
}

// folded biases: bm2[n] = mb[n] + sum_k mw[n][k]*yb[k%256] — 1 wave per output
__global__ void k_foldbias(const float* __restrict__ mw, const float* __restrict__ gw,
                           const float* __restrict__ mb, const float* __restrict__ gb,
                           const float* __restrict__ yb,
                           float* __restrict__ bm2, float* __restrict__ bg2)
{
    int row = blockIdx.x;         // 0..511
    int lane = threadIdx.x;       // 0..63
    int n = row & 255;
    const float* W = (row < 256) ? mw : gw;
    float s = 0.f;
    for (int k = lane; k < 1024; k += 64)
        s = fmaf(W[(size_t)n * 1024 + k], yb[k & 255], s);
    for (int off = 32; off; off >>= 1) s += __shfl_down(s, off);
    if (lane == 0) {
        if (row < 256) bm2[n] = s + mb[n];
        else           bg2[n] = s + gb[n];
    }
}

// ---------------- transpose x to bf16 two-plane row-major XT[p][192]:
// k 0..95 = bf16_hi(x[ch]), k 96..191 = bf16_lo residual. p = b*LL + l.
__global__ __launch_bounds__(256) void k_xpose(
    const float* __restrict__ x, unsigned short* __restrict__ XT)
{
    int t = threadIdx.x;
    int p0 = blockIdx.x * 256;
    int b = p0 >> 14;
    int l = (p0 & (LL - 1)) + t;
    size_t gp = (size_t)(p0 + t);
    const float* xr = x + (size_t)b * 96 * LL + l;
    unsigned short* orow = XT + gp * 192;
#pragma unroll
    for (int kq = 0; kq < 12; ++kq) {
        short8v hi, lo;
#pragma unroll
        for (int c = 0; c < 8; ++c) {
            float v = xr[(size_t)(kq * 8 + c) * LL];
            unsigned short h = f2b(v);
            float r = v - b2f(h);
            hi[c] = (short)h;
            lo[c] = (short)f2b(r);
        }
        *(short8v*)(orow + kq * 8) = hi;
        *(short8v*)(orow + 96 + kq * 8) = lo;
    }
}

// ---------------- pack in-proj weights bf16 row-major WPT[r'][192], both halves = w_hi:
// r' = nn16*64 + g*16 + ni  (g: 0=xw,1=B,2=C,3=delta; n = nn16*16+ni)
__global__ void k_wprep(
    const float* __restrict__ xw, const float* __restrict__ bcw, const float* __restrict__ dw,
    unsigned short* __restrict__ WPT)
{
    int rp = blockIdx.x * 32 + (threadIdx.x >> 3);   // 0..1023
    int sub = threadIdx.x & 7;
    int nn16 = rp >> 6, g = (rp >> 4) & 3, ni = rp & 15;
    int n = nn16 * 16 + ni;
    const float* row;
    if (g == 0)      row = xw + (size_t)n * 96;
    else if (g == 1) row = bcw + (size_t)n * 96;
    else if (g == 2) row = bcw + (size_t)(256 + n) * 96;
    else             row = dw + (size_t)n * 96;
    unsigned short* orow = WPT + (size_t)rp * 192;
    for (int kq = sub; kq < 12; kq += 8) {
        short8v hv;
#pragma unroll
        for (int c = 0; c < 8; ++c) hv[c] = (short)f2b(row[kq * 8 + c]);
        *(short8v*)(orow + kq * 8) = hv;
        *(short8v*)(orow + 96 + kq * 8) = hv;
    }
}

// ---------------- pack out-proj weights bf16 OWB[128][256] (rows 96..127 zero)
__global__ void k_owprep(const float* __restrict__ ow, unsigned short* __restrict__ OWB)
{
    int r = blockIdx.x;           // 0..127
    int lane = threadIdx.x;       // 0..63
    unsigned short pk[4];
    if (r < 96) {
        float4 v = *(const float4*)(ow + (size_t)r * 256 + lane * 4);
        pk[0] = f2b(v.x); pk[1] = f2b(v.y); pk[2] = f2b(v.z); pk[3] = f2b(v.w);
    } else {
        pk[0] = pk[1] = pk[2] = pk[3] = 0;
    }
    *(unsigned long long*)(&OWB[(size_t)r * 256 + lane * 4]) = *(const unsigned long long*)pk;
}

// ---------------- in-projection via MFMA (K=192):
// A = XT[p][192], B = WPT[r'][192]. dot = (x_hi+x_lo)@w_hi = f32-grade x, bf16 w.
__global__ __launch_bounds__(256) void k_proj_mfma(
    const unsigned short* __restrict__ XT, const unsigned short* __restrict__ WPT,
    const float* __restrict__ xb, const float* __restrict__ bcb, const float* __restrict__ db,
    unsigned int* __restrict__ AB, unsigned short* __restrict__ C)
{
    __shared__ __align__(16) unsigned short smA[128 * 32];   // [row][k] bf16, 8 KB
    __shared__ __align__(16) unsigned short smB[128 * 32];   // [r' row][k] bf16, 8 KB
    int tid = threadIdx.x;
    int w = tid >> 6, l = tid & 63;
    int mt = blockIdx.x;          // 256 row tiles of 128 positions
    int bnt = blockIdx.y;         // 8 r' tiles of 128
    int p0 = mt * 128;
    int bn0 = bnt * 128;

    int rowA = tid >> 2;          // 0..63
    int chA  = tid & 3;
    int laneRow = l & 15;
    int laneK   = l >> 4;

    float4v acc[2][8];
#pragma unroll
    for (int i = 0; i < 2; ++i)
#pragma unroll
        for (int f = 0; f < 8; ++f) acc[i][f] = (float4v)0.f;

    for (int kt = 0; kt < 6; ++kt) {
        const unsigned short* gA = XT + (size_t)(p0 + rowA) * 192 + kt * 32 + chA * 8;
        const unsigned short* gB = WPT + (size_t)(bn0 + rowA) * 192 + kt * 32 + chA * 8;
        GLL16(gA,            smA + tid * 8);
        GLL16(gA + 64 * 192, smA + 2048 + tid * 8);
        GLL16(gB,            smB + tid * 8);
        GLL16(gB + 64 * 192, smB + 2048 + tid * 8);
        __syncthreads();

        short8v a0 = *(const short8v*)(&smA[(w * 32 + laneRow) * 32 + laneK * 8]);
        short8v a1 = *(const short8v*)(&smA[(w * 32 + 16 + laneRow) * 32 + laneK * 8]);
#pragma unroll
        for (int f = 0; f < 8; ++f) {
            short8v bf_ = *(const short8v*)(&smB[(f * 16 + laneRow) * 32 + laneK * 8]);
            acc[0][f] = __builtin_amdgcn_mfma_f32_16x16x32_bf16(a0, bf_, acc[0][f], 0, 0, 0);
            acc[1][f] = __builtin_amdgcn_mfma_f32_16x16x32_bf16(a1, bf_, acc[1][f], 0, 0, 0);
        }
        __syncthreads();
    }

    int lr = l >> 4, lc = l & 15;
#pragma unroll
    for (int mr = 0; mr < 2; ++mr) {
#pragma unroll
        for (int nn2 = 0; nn2 < 2; ++nn2) {
            int n = (bnt * 2 + nn2) * 16 + lc;
            float xbv = xb[n], bb = bcb[n], cb = bcb[256 + n], dbv = db[n];
#pragma unroll
            for (int q = 0; q < 4; ++q) {
                int p = p0 + w * 32 + mr * 16 + lr * 4 + q;
                float u  = acc[mr][nn2 * 4 + 0][q] + xbv;
                float Bm = acc[mr][nn2 * 4 + 1][q] + bb;
                float Cm = acc[mr][nn2 * 4 + 2][q] + cb;
                float dl = acc[mr][nn2 * 4 + 3][q] + dbv;
                float a  = 1.0f / (1.0f + __expf(dl));   // exp(-softplus(d)) == sigmoid(-d)
                float bu = (1.0f - a) * Bm * u;
                size_t base = (size_t)p * NLAT + n;      // p == b*LL + l
                AB[base] = (unsigned int)f2b(a) | ((unsigned int)f2b(bu) << 16);
                C[base]  = f2b(Cm);
            }
        }
    }
}

__device__ __forceinline__ int src_pos(int d, int t) {
    int s = (d >= 2) ? (LL - 1 - t) : t;
    return (d & 1) ? (((s & 127) << 7) | (s >> 7)) : s;   // dirs 1,3 traverse transposed order
}

// ---------------- scan pass 1: per-chunk aggregates (A_prod, B_acc)
__global__ __launch_bounds__(256) void k_scan1(
    const unsigned int* __restrict__ AB,
    float* __restrict__ AggA, float* __restrict__ AggB)
{
    int n = threadIdx.x;
    int c = blockIdx.x, d = blockIdx.y, b = blockIdx.z;
    float h = 0.f, Ap = 1.f;
    int t0 = c * 256;
#pragma unroll 4
    for (int i = 0; i < 256; ++i) {
        int ls = src_pos(d, t0 + i);
        unsigned int v = AB[((size_t)b * LL + ls) * NLAT + n];
        float a  = __uint_as_float(v << 16);
        float bu = __uint_as_float(v & 0xFFFF0000u);
        h = fmaf(a, h, bu);
        Ap *= a;
    }
    size_t o = (((size_t)b * 4 + d) * 64 + c) * NLAT + n;
    AggA[o] = Ap; AggB[o] = h;
}

// ---------------- scan pass 2: serial scan over 64 chunk aggregates
__global__ void k_scan2(const float* __restrict__ AggA, const float* __restrict__ AggB,
                        float* __restrict__ Hs)
{
    int n = threadIdx.x;
    int d = blockIdx.x, b = blockIdx.y;
    float h = 0.f;
    for (int c = 0; c < 64; ++c) {
        size_t o = (((size_t)b * 4 + d) * 64 + c) * NLAT + n;
        Hs[o] = h;
        h = fmaf(AggA[o], h, AggB[o]);
    }
}

// ---------------- scan pass 3: replay with true h_in, y = C*h
__global__ __launch_bounds__(256) void k_scan3(
    const unsigned int* __restrict__ AB, const unsigned short* __restrict__ C,
    const float* __restrict__ Hs, unsigned short* __restrict__ ys)
{
    int n = threadIdx.x;
    int c = blockIdx.x, d = blockIdx.y, b = blockIdx.z;
    size_t o = (((size_t)b * 4 + d) * 64 + c) * NLAT + n;
    float h = Hs[o];
    int t0 = c * 256;
    size_t ybase = (((size_t)b * 4 + d) * LL + t0) * NLAT + n;
#pragma unroll 4
    for (int i = 0; i < 256; ++i) {
        int ls = src_pos(d, t0 + i);
        size_t idx = ((size_t)b * LL + ls) * NLAT + n;
        unsigned int v = AB[idx];
        float a  = __uint_as_float(v << 16);
        float bu = __uint_as_float(v & 0xFFFF0000u);
        h = fmaf(a, h, bu);
        float y = b2f(C[idx]) * h;
        ys[ybase + (size_t)i * NLAT] = f2b(y);
    }
}

// ---------------- merge (MFMA bf16): z = (ys_cat@WM + bm2) * sigmoid(ys_cat@WG + bg2)
__global__ __launch_bounds__(256) void k_merge_mfma(
    const unsigned short* __restrict__ ys,
    const unsigned short* __restrict__ WBT,
    const float* __restrict__ bm2, const float* __restrict__ bg2,
    unsigned short* __restrict__ z)
{
    __shared__ __align__(16) unsigned short smA[128 * 32];   // [row][k] bf16, 8 KB
    __shared__ __align__(16) unsigned short smB[128 * 32];   // [colInTile][k] bf16, 8 KB
    int tid = threadIdx.x;
    int w = tid >> 6, l = tid & 63;
    int mt = blockIdx.x;          // 0..255 row tiles
    int nt = blockIdx.y;          // 0..3 n tiles of 64
    int p0 = mt * 128;
    int b4 = (p0 >> 14) * 4;
    int l0 = p0 & (LL - 1);
    int n0 = nt * 64;

    int rowA = tid >> 2;          // 0..63
    int chA  = tid & 3;
    int laneRow = l & 15;
    int laneK   = l >> 4;

    float4v accM[2][4], accG[2][4];
#pragma unroll
    for (int i = 0; i < 2; ++i)
#pragma unroll
        for (int j = 0; j < 4; ++j) { accM[i][j] = (float4v)0.f; accG[i][j] = (float4v)0.f; }

    for (int kt = 0; kt < 32; ++kt) {
        int d = kt >> 3;
        int j0k = (kt & 7) * 32;
        const unsigned short* gA = ys + (((size_t)(b4 + d)) * LL + l0 + rowA) * 256 + j0k + chA * 8;
        const unsigned short* gB = WBT + ((size_t)(n0 + rowA)) * 1024 + kt * 32 + chA * 8;
        GLL16(gA,              smA + tid * 8);
        GLL16(gA + 64 * 256,   smA + 2048 + tid * 8);
        GLL16(gB,              smB + tid * 8);
        GLL16(gB + 256 * 1024, smB + 2048 + tid * 8);
        __syncthreads();

        short8v a0 = *(const short8v*)(&smA[(w * 32 + laneRow) * 32 + laneK * 8]);
        short8v a1 = *(const short8v*)(&smA[(w * 32 + 16 + laneRow) * 32 + laneK * 8]);
#pragma unroll
        for (int nr = 0; nr < 4; ++nr) {
            short8v bm_ = *(const short8v*)(&smB[(nr * 16 + laneRow) * 32 + laneK * 8]);
            short8v bg_ = *(const short8v*)(&smB[(64 + nr * 16 + laneRow) * 32 + laneK * 8]);
            accM[0][nr] = __builtin_amdgcn_mfma_f32_16x16x32_bf16(a0, bm_, accM[0][nr], 0, 0, 0);
            accM[1][nr] = __builtin_amdgcn_mfma_f32_16x16x32_bf16(a1, bm_, accM[1][nr], 0, 0, 0);
            accG[0][nr] = __builtin_amdgcn_mfma_f32_16x16x32_bf16(a0, bg_, accG[0][nr], 0, 0, 0);
            accG[1][nr] = __builtin_amdgcn_mfma_f32_16x16x32_bf16(a1, bg_, accG[1][nr], 0, 0, 0);
        }
        __syncthreads();
    }

    int lr = l >> 4, lc = l & 15;
#pragma unroll
    for (int mr = 0; mr < 2; ++mr) {
#pragma unroll
        for (int nr = 0; nr < 4; ++nr) {
            int n = n0 + nr * 16 + lc;
            float bmv = bm2[n], bgv = bg2[n];
#pragma unroll
            for (int q = 0; q < 4; ++q) {
                int p = p0 + w * 32 + mr * 16 + lr * 4 + q;
                float m = accM[mr][nr][q] + bmv;
                float g = accG[mr][nr][q] + bgv;
                float zv = m / (1.f + __expf(-g));
                z[(size_t)p * NLAT + n] = f2b(zv);
            }
        }
    }
}

// ---------------- out projection via MFMA (K=256):
// A = Z[p][256] bf16, B = OWB[c][256] bf16 (128 rows, 96 real).
__global__ __launch_bounds__(256) void k_out_mfma(
    const unsigned short* __restrict__ z, const unsigned short* __restrict__ OWB,
    const float* __restrict__ ob, float* __restrict__ out)
{
    __shared__ __align__(16) unsigned short smA[128 * 32];   // [row][k] bf16, 8 KB
    __shared__ __align__(16) unsigned short smB[128 * 32];   // [ch row][k] bf16, 8 KB
    int tid = threadIdx.x;
    int w = tid >> 6, l = tid & 63;
    int p0 = blockIdx.x * 128;
    int b = p0 >> 14;
    int l0 = p0 & (LL - 1);

    int rowA = tid >> 2;          // 0..63
    int chA  = tid & 3;
    int laneRow = l & 15;
    int laneK   = l >> 4;

    float4v acc[2][6];
#pragma unroll
    for (int i = 0; i < 2; ++i)
#pragma unroll
        for (int f = 0; f < 6; ++f) acc[i][f] = (float4v)0.f;

    for (int kt = 0; kt < 8; ++kt) {
        const unsigned short* gA = z + (size_t)(p0 + rowA) * 256 + kt * 32 + chA * 8;
        const unsigned short* gB = OWB + (size_t)rowA * 256 + kt * 32 + chA * 8;
        GLL16(gA,            smA + tid * 8);
        GLL16(gA + 64 * 256, smA + 2048 + tid * 8);
        GLL16(gB,            smB + tid * 8);
        GLL16(gB + 64 * 256, smB + 2048 + tid * 8);
        __syncthreads();

        short8v a0 = *(const short8v*)(&smA[(w * 32 + laneRow) * 32 + laneK * 8]);
        short8v a1 = *(const short8v*)(&smA[(w * 32 + 16 + laneRow) * 32 + laneK * 8]);
#pragma unroll
        for (int nr = 0; nr < 6; ++nr) {
            short8v bf_ = *(const short8v*)(&smB[(nr * 16 + laneRow) * 32 + laneK * 8]);
            acc[0][nr] = __builtin_amdgcn_mfma_f32_16x16x32_bf16(a0, bf_, acc[0][nr], 0, 0, 0);
            acc[1][nr] = __builtin_amdgcn_mfma_f32_16x16x32_bf16(a1, bf_, acc[1][nr], 0, 0, 0);
        }
        __syncthreads();
    }

    int lr = l >> 4, lc = l & 15;
#pragma unroll
    for (int mr = 0; mr < 2; ++mr) {
#pragma unroll
        for (int nr = 0; nr < 6; ++nr) {
            int c = nr * 16 + lc;
            float obv = ob[c];
            int ll = l0 + w * 32 + mr * 16 + lr * 4;
            float4 v;
            v.x = acc[mr][nr][0] + obv;
            v.y = acc[mr][nr][1] + obv;
            v.z = acc[mr][nr][2] + obv;
            v.w = acc[mr][nr][3] + obv;
            *(float4*)(&out[((size_t)(b * 96 + c)) * LL + ll]) = v;
        }
    }
}

extern "C" void kernel_launch(void* const* d_in, const int* in_sizes, int n_in,
                              void* d_out, int out_size, void* d_ws, size_t ws_size,
                              hipStream_t stream) {
    (void)in_sizes; (void)n_in; (void)out_size; (void)ws_size;
    const float* x   = (const float*)d_in[0];
    const float* xw  = (const float*)d_in[1];
    const float* xb  = (const float*)d_in[2];
    const float* bcw = (const float*)d_in[3];
    const float* bcb = (const float*)d_in[4];
    const float* dw  = (const float*)d_in[5];
    const float* db  = (const float*)d_in[6];
    const float* yw  = (const float*)d_in[7];
    const float* yb  = (const float*)d_in[8];
    const float* mw  = (const float*)d_in[9];
    const float* mb  = (const float*)d_in[10];
    const float* gw  = (const float*)d_in[11];
    const float* gb  = (const float*)d_in[12];
    const float* ow  = (const float*)d_in[13];
    const float* ob  = (const float*)d_in[14];
    float* out = (float*)d_out;

    char* ws = (char*)d_ws;
    size_t off = 0;
    auto alloc = [&](size_t bytes) -> void* {
        void* p = ws + off;
        off += (bytes + 255) & ~(size_t)255;
        return p;
    };
    unsigned int*   AB  = (unsigned int*)  alloc((size_t)NB * LL * NLAT * 4);     // 33.6 MB
    unsigned short* C   = (unsigned short*)alloc((size_t)NB * LL * NLAT * 2);     // 16.8 MB
    unsigned short* YS  = (unsigned short*)alloc((size_t)NB * 4 * LL * NLAT * 2); // 67 MB
    unsigned short* Z   = (unsigned short*)alloc((size_t)NB * LL * NLAT * 2);     // 16.8 MB
    unsigned short* WBT = (unsigned short*)alloc((size_t)512 * 1024 * 2);         // 1 MB
    unsigned short* XT  = (unsigned short*)alloc((size_t)NB * LL * 192 * 2);      // 12.6 MB
    unsigned short* WPT = (unsigned short*)alloc((size_t)1024 * 192 * 2);         // 0.39 MB
    unsigned short* OWB = (unsigned short*)alloc((size_t)128 * 256 * 2);          // 64 KB
    float* WF   = (float*)alloc((size_t)4 * 512 * 1024 * 4);                      // 8 MB
    float* BM2  = (float*)alloc(256 * 4);
    float* BG2  = (float*)alloc(256 * 4);
    float* AggA = (float*)alloc((size_t)NB * 4 * 64 * NLAT * 4);
    float* AggB = (float*)alloc((size_t)NB * 4 * 64 * NLAT * 4);
    float* HS   = (float*)alloc((size_t)NB * 4 * 64 * NLAT * 4);

    k_foldw_part<<<dim3(4, 4, 32),  256, 0, stream>>>(yw, mw, gw, WF);
    k_foldsum   <<<512,             256, 0, stream>>>(WF, WBT);
    k_foldbias  <<<512,              64, 0, stream>>>(mw, gw, mb, gb, yb, BM2, BG2);
    k_wprep     <<<32,              256, 0, stream>>>(xw, bcw, dw, WPT);
    k_owprep    <<<128,              64, 0, stream>>>(ow, OWB);
    k_xpose     <<<128,             256, 0, stream>>>(x, XT);
    k_proj_mfma <<<dim3(256, 8),    256, 0, stream>>>(XT, WPT, xb, bcb, db, AB, C);
    k_scan1     <<<dim3(64, 4, NB), 256, 0, stream>>>(AB, AggA, AggB);
    k_scan2     <<<dim3(4, NB),     256, 0, stream>>>(AggA, AggB, HS);
    k_scan3     <<<dim3(64, 4, NB), 256, 0, stream>>>(AB, C, HS, YS);
    k_merge_mfma<<<dim3(256, 4),    256, 0, stream>>>(YS, WBT, BM2, BG2, Z);
    k_out_mfma  <<<256,             256, 0, stream>>>(Z, OWB, ob, out);
}

// Round 8
// 198.330 us; speedup vs baseline: 4.2318x; 1.0127x over previous
//
#include <hip/hip_runtime.h>
#include <stdint.h>

#define LL 16384
#define NB 2
#define CIN 96
#define NLAT 256
#define COUT 96

typedef __attribute__((ext_vector_type(8))) short short8v;
typedef __attribute__((ext_vector_type(4))) float float4v;

__device__ __forceinline__ float b2f(unsigned short h) {
    return __uint_as_float(((unsigned int)h) << 16);
}
__device__ __forceinline__ unsigned short f2b(float f) {
    unsigned int u = __float_as_uint(f);
    unsigned int r = (u + 0x7FFFu + ((u >> 16) & 1u)) >> 16;
    return (unsigned short)r;
}

#define GLL16(g, s) __builtin_amdgcn_global_load_lds( \
    (const __attribute__((address_space(1))) unsigned int*)(g), \
    (__attribute__((address_space(3))) unsigned int*)(s), 16, 0, 0)

// ---------------- fold weights, split-K partials
__global__ __launch_bounds__(256) void k_foldw_part(
    const float* __restrict__ yw, const float* __restrict__ mw, const float* __restrict__ gw,
    float* __restrict__ WF)
{
    __shared__ float At[64][68];
    __shared__ float Bt[64][68];
    int jt = blockIdx.x, nt = blockIdx.y, dzk = blockIdx.z;
    int kc = dzk & 3, dz = dzk >> 2;
    int d = dz & 3, mat = dz >> 2;
    const float* src = mat ? gw : mw;
    int j0 = jt * 64, n0 = nt * 64;
    int tid = threadIdx.x, tx = tid & 15, ty = tid >> 4;
    float acc[4][4] = {};
    int i0 = kc * 64;
    for (int rep = 0; rep < 16; ++rep) {
        int idx = rep * 256 + tid;
        int r = idx >> 6, cq = idx & 63;
        At[r][cq] = yw[(size_t)(i0 + r) * 256 + j0 + cq];
        Bt[cq][r] = src[(size_t)(n0 + r) * 1024 + d * 256 + i0 + cq];
    }
    __syncthreads();
    for (int ii = 0; ii < 64; ++ii) {
        float4 a4 = *(const float4*)(&At[ii][ty * 4]);
        float4 b4 = *(const float4*)(&Bt[ii][tx * 4]);
        float av[4] = {a4.x, a4.y, a4.z, a4.w};
        float bv[4] = {b4.x, b4.y, b4.z, b4.w};
        for (int q = 0; q < 4; ++q)
            for (int p = 0; p < 4; ++p)
                acc[q][p] = fmaf(av[q], bv[p], acc[q][p]);
    }
    float* dst = WF + (size_t)kc * 512 * 1024;
    for (int q = 0; q < 4; ++q) {
        int k = d * 256 + j0 + ty * 4 + q;
        for (int p = 0; p < 4; ++p) {
            int n = n0 + tx * 4 + p;
            dst[(size_t)(mat * 256 + n) * 1024 + k] = acc[q][p];
        }
    }
}

// sum the 4 split-K partials, round to bf16
__global__ __launch_bounds__(256) void k_foldsum(
    const float* __restrict__ WF, unsigned short* __restrict__ WBT)
{
    int t = blockIdx.x * 256 + threadIdx.x;
    size_t o = (size_t)t * 4;
    const size_t S = (size_t)512 * 1024;
    float4 s0 = *(const float4*)(WF + o);
    float4 s1 = *(const float4*)(WF + S + o);
    float4 s2 = *(const float4*)(WF + 2 * S + o);
    float4 s3 = *(const float4*)(WF + 3 * S + o);
    unsigned short pk[4];
    pk[0] = f2b(s0.x + s1.x + s2.x + s3.x);
    pk[1] = f2b(s0.y + s1.y + s2.y + s3.y);
    pk[2] = f2b(s0.z + s1.z + s2.z + s3.z);
    pk[3] = f2b(s0.w + s1.w + s2.w + s3.w);
    *(unsigned long long*)(&WBT[o]) = *(const unsigned long long*)pk;
}

// folded biases: one wave per output row
__global__ void k_foldbias(const float* __restrict__ mw, const float* __restrict__ gw,
                           const float* __restrict__ mb, const float* __restrict__ gb,
                           const float* __restrict__ yb,
                           float* __restrict__ bm2, float* __restrict__ bg2)
{
    int row = blockIdx.x;
    int lane = threadIdx.x;
    int n = row & 255;
    const float* W = (row < 256) ? mw : gw;
    float s = 0.f;
    for (int k = lane; k < 1024; k += 64)
        s = fmaf(W[(size_t)n * 1024 + k], yb[k & 255], s);
    for (int off = 32; off; off >>= 1) s += __shfl_down(s, off);
    if (lane == 0) {
        if (row < 256) bm2[n] = s + mb[n];
        else           bg2[n] = s + gb[n];
    }
}

// ---------------- transpose x to bf16 two-plane row-major XT[p][192]
// grid 512: 64 positions/block x 4 kq-groups (3 kq each)
__global__ __launch_bounds__(256) void k_xpose(
    const float* __restrict__ x, unsigned short* __restrict__ XT)
{
    int t = threadIdx.x;
    int pl = t & 63;
    int grp = t >> 6;
    int p0 = blockIdx.x * 64;
    int b = p0 >> 14;
    int l = (p0 & (LL - 1)) + pl;
    size_t gp = (size_t)(p0 + pl);
    const float* xr = x + (size_t)b * 96 * LL + l;
    unsigned short* orow = XT + gp * 192;
#pragma unroll
    for (int kk = 0; kk < 3; ++kk) {
        int kq = grp * 3 + kk;
        short8v hi, lo;
#pragma unroll
        for (int c = 0; c < 8; ++c) {
            float v = xr[(size_t)(kq * 8 + c) * LL];
            unsigned short h = f2b(v);
            float r = v - b2f(h);
            hi[c] = (short)h;
            lo[c] = (short)f2b(r);
        }
        *(short8v*)(orow + kq * 8) = hi;
        *(short8v*)(orow + 96 + kq * 8) = lo;
    }
}

// ---------------- pack in-proj weights bf16 row-major WPT[r'][192]
__global__ void k_wprep(
    const float* __restrict__ xw, const float* __restrict__ bcw, const float* __restrict__ dw,
    unsigned short* __restrict__ WPT)
{
    int rp = blockIdx.x * 32 + (threadIdx.x >> 3);
    int sub = threadIdx.x & 7;
    int nn16 = rp >> 6, g = (rp >> 4) & 3, ni = rp & 15;
    int n = nn16 * 16 + ni;
    const float* row;
    if (g == 0)      row = xw + (size_t)n * 96;
    else if (g == 1) row = bcw + (size_t)n * 96;
    else if (g == 2) row = bcw + (size_t)(256 + n) * 96;
    else             row = dw + (size_t)n * 96;
    unsigned short* orow = WPT + (size_t)rp * 192;
    for (int kq = sub; kq < 12; kq += 8) {
        short8v hv;
#pragma unroll
        for (int c = 0; c < 8; ++c) hv[c] = (short)f2b(row[kq * 8 + c]);
        *(short8v*)(orow + kq * 8) = hv;
        *(short8v*)(orow + 96 + kq * 8) = hv;
    }
}

// ---------------- pack out-proj weights bf16 OWB[128][256]
__global__ void k_owprep(const float* __restrict__ ow, unsigned short* __restrict__ OWB)
{
    int r = blockIdx.x;
    int lane = threadIdx.x;
    unsigned short pk[4];
    if (r < 96) {
        float4 v = *(const float4*)(ow + (size_t)r * 256 + lane * 4);
        pk[0] = f2b(v.x); pk[1] = f2b(v.y); pk[2] = f2b(v.z); pk[3] = f2b(v.w);
    } else {
        pk[0] = pk[1] = pk[2] = pk[3] = 0;
    }
    *(unsigned long long*)(&OWB[(size_t)r * 256 + lane * 4]) = *(const unsigned long long*)pk;
}

// ---------------- in-projection via MFMA (K=192) — validated round-5 template
__global__ __launch_bounds__(256) void k_proj_mfma(
    const unsigned short* __restrict__ XT, const unsigned short* __restrict__ WPT,
    const float* __restrict__ xb, const float* __restrict__ bcb, const float* __restrict__ db,
    unsigned int* __restrict__ AB, unsigned short* __restrict__ C)
{
    __shared__ __align__(16) unsigned short smA[128 * 32];
    __shared__ __align__(16) unsigned short smB[128 * 32];
    int tid = threadIdx.x;
    int w = tid >> 6, l = tid & 63;
    int mt = blockIdx.x;
    int bnt = blockIdx.y;
    int p0 = mt * 128;
    int bn0 = bnt * 128;

    int rowA = tid >> 2;
    int chA  = tid & 3;
    int laneRow = l & 15;
    int laneK   = l >> 4;

    float4v acc[2][8];
#pragma unroll
    for (int i = 0; i < 2; ++i)
#pragma unroll
        for (int f = 0; f < 8; ++f) acc[i][f] = (float4v)0.f;

    for (int kt = 0; kt < 6; ++kt) {
        const unsigned short* gA = XT + (size_t)(p0 + rowA) * 192 + kt * 32 + chA * 8;
        const unsigned short* gB = WPT + (size_t)(bn0 + rowA) * 192 + kt * 32 + chA * 8;
        GLL16(gA,            smA + tid * 8);
        GLL16(gA + 64 * 192, smA + 2048 + tid * 8);
        GLL16(gB,            smB + tid * 8);
        GLL16(gB + 64 * 192, smB + 2048 + tid * 8);
        __syncthreads();

        short8v a0 = *(const short8v*)(&smA[(w * 32 + laneRow) * 32 + laneK * 8]);
        short8v a1 = *(const short8v*)(&smA[(w * 32 + 16 + laneRow) * 32 + laneK * 8]);
#pragma unroll
        for (int f = 0; f < 8; ++f) {
            short8v bf_ = *(const short8v*)(&smB[(f * 16 + laneRow) * 32 + laneK * 8]);
            acc[0][f] = __builtin_amdgcn_mfma_f32_16x16x32_bf16(a0, bf_, acc[0][f], 0, 0, 0);
            acc[1][f] = __builtin_amdgcn_mfma_f32_16x16x32_bf16(a1, bf_, acc[1][f], 0, 0, 0);
        }
        __syncthreads();
    }

    int lr = l >> 4, lc = l & 15;
#pragma unroll
    for (int mr = 0; mr < 2; ++mr) {
#pragma unroll
        for (int nn2 = 0; nn2 < 2; ++nn2) {
            int n = (bnt * 2 + nn2) * 16 + lc;
            float xbv = xb[n], bb = bcb[n], cb = bcb[256 + n], dbv = db[n];
#pragma unroll
            for (int q = 0; q < 4; ++q) {
                int p = p0 + w * 32 + mr * 16 + lr * 4 + q;
                float u  = acc[mr][nn2 * 4 + 0][q] + xbv;
                float Bm = acc[mr][nn2 * 4 + 1][q] + bb;
                float Cm = acc[mr][nn2 * 4 + 2][q] + cb;
                float dl = acc[mr][nn2 * 4 + 3][q] + dbv;
                float a  = 1.0f / (1.0f + __expf(dl));
                float bu = (1.0f - a) * Bm * u;
                size_t base = (size_t)p * NLAT + n;
                AB[base] = (unsigned int)f2b(a) | ((unsigned int)f2b(bu) << 16);
                C[base]  = f2b(Cm);
            }
        }
    }
}

__device__ __forceinline__ int src_pos(int d, int t) {
    int s = (d >= 2) ? (LL - 1 - t) : t;
    return (d & 1) ? (((s & 127) << 7) | (s >> 7)) : s;
}

// ---------------- scan pass 1
__global__ __launch_bounds__(256) void k_scan1(
    const unsigned int* __restrict__ AB,
    float* __restrict__ AggA, float* __restrict__ AggB)
{
    int n = threadIdx.x;
    int c = blockIdx.x, d = blockIdx.y, b = blockIdx.z;
    float h = 0.f, Ap = 1.f;
    int t0 = c * 256;
#pragma unroll 4
    for (int i = 0; i < 256; ++i) {
        int ls = src_pos(d, t0 + i);
        unsigned int v = AB[((size_t)b * LL + ls) * NLAT + n];
        float a  = __uint_as_float(v << 16);
        float bu = __uint_as_float(v & 0xFFFF0000u);
        h = fmaf(a, h, bu);
        Ap *= a;
    }
    size_t o = (((size_t)b * 4 + d) * 64 + c) * NLAT + n;
    AggA[o] = Ap; AggB[o] = h;
}

// ---------------- scan pass 2
__global__ void k_scan2(const float* __restrict__ AggA, const float* __restrict__ AggB,
                        float* __restrict__ Hs)
{
    int n = threadIdx.x;
    int d = blockIdx.x, b = blockIdx.y;
    float h = 0.f;
    for (int c = 0; c < 64; ++c) {
        size_t o = (((size_t)b * 4 + d) * 64 + c) * NLAT + n;
        Hs[o] = h;
        h = fmaf(AggA[o], h, AggB[o]);
    }
}

// ---------------- scan pass 3
__global__ __launch_bounds__(256) void k_scan3(
    const unsigned int* __restrict__ AB, const unsigned short* __restrict__ C,
    const float* __restrict__ Hs, unsigned short* __restrict__ ys)
{
    int n = threadIdx.x;
    int c = blockIdx.x, d = blockIdx.y, b = blockIdx.z;
    size_t o = (((size_t)b * 4 + d) * 64 + c) * NLAT + n;
    float h = Hs[o];
    int t0 = c * 256;
    size_t ybase = (((size_t)b * 4 + d) * LL + t0) * NLAT + n;
#pragma unroll 4
    for (int i = 0; i < 256; ++i) {
        int ls = src_pos(d, t0 + i);
        size_t idx = ((size_t)b * LL + ls) * NLAT + n;
        unsigned int v = AB[idx];
        float a  = __uint_as_float(v << 16);
        float bu = __uint_as_float(v & 0xFFFF0000u);
        h = fmaf(a, h, bu);
        float y = b2f(C[idx]) * h;
        ys[ybase + (size_t)i * NLAT] = f2b(y);
    }
}

// ---------------- merge (MFMA bf16, BK=64 + chunk-XOR swizzle):
// z = (ys_cat@WM + bm2) * sigmoid(ys_cat@WG + bg2)
// LDS rows are 64 elems (128B); physical chunk c_p holds global chunk c_p^(row&7).
__global__ __launch_bounds__(256) void k_merge_mfma(
    const unsigned short* __restrict__ ys,
    const unsigned short* __restrict__ WBT,
    const float* __restrict__ bm2, const float* __restrict__ bg2,
    unsigned short* __restrict__ z)
{
    __shared__ __align__(16) unsigned short smA[128 * 64];   // 16 KB
    __shared__ __align__(16) unsigned short smB[128 * 64];   // 16 KB
    int tid = threadIdx.x;
    int w = tid >> 6, l = tid & 63;
    int mt = blockIdx.x;          // 0..255 row tiles
    int nt = blockIdx.y;          // 0..3 n tiles of 64
    int p0 = mt * 128;
    int b4 = (p0 >> 14) * 4;
    int l0 = p0 & (LL - 1);
    int n0 = nt * 64;

    int rowS = tid >> 3;          // 0..31: staging row within 32-row group
    int cg   = (tid & 7) ^ (rowS & 7);   // swizzled global chunk (same all reps)
    int laneRow = l & 15;
    int laneK   = l >> 4;
    int rx8 = (laneRow & 7);      // row&7 for all fragment reads

    float4v accM[2][4], accG[2][4];
#pragma unroll
    for (int i = 0; i < 2; ++i)
#pragma unroll
        for (int j = 0; j < 4; ++j) { accM[i][j] = (float4v)0.f; accG[i][j] = (float4v)0.f; }

    for (int kt = 0; kt < 16; ++kt) {
        int d = kt >> 2;
        int j0k = (kt & 3) * 64;
        // A: 128 rows x 64 elems; rep r covers rows r*32..r*32+31
        const unsigned short* gAb = ys + (((size_t)(b4 + d)) * LL + l0) * 256 + j0k + cg * 8;
#pragma unroll
        for (int rep = 0; rep < 4; ++rep) {
            GLL16(gAb + (size_t)(rep * 32 + rowS) * 256, smA + rep * 2048 + tid * 8);
        }
        // B: rows 0..63 = WM[n0..n0+63], rows 64..127 = WG
#pragma unroll
        for (int rep = 0; rep < 4; ++rep) {
            int rr = rep * 32 + rowS;
            int nrow = (rr < 64) ? (n0 + rr) : (256 + n0 + rr - 64);
            GLL16(WBT + (size_t)nrow * 1024 + kt * 64 + cg * 8, smB + rep * 2048 + tid * 8);
        }
        __syncthreads();

#pragma unroll
        for (int ksub = 0; ksub < 2; ++ksub) {
            int cxo = ((ksub * 4 + laneK) ^ rx8) * 8;
            short8v a0 = *(const short8v*)(&smA[(w * 32 + laneRow) * 64 + cxo]);
            short8v a1 = *(const short8v*)(&smA[(w * 32 + 16 + laneRow) * 64 + cxo]);
#pragma unroll
            for (int nr = 0; nr < 4; ++nr) {
                short8v bm_ = *(const short8v*)(&smB[(nr * 16 + laneRow) * 64 + cxo]);
                short8v bg_ = *(const short8v*)(&smB[(64 + nr * 16 + laneRow) * 64 + cxo]);
                accM[0][nr] = __builtin_amdgcn_mfma_f32_16x16x32_bf16(a0, bm_, accM[0][nr], 0, 0, 0);
                accM[1][nr] = __builtin_amdgcn_mfma_f32_16x16x32_bf16(a1, bm_, accM[1][nr], 0, 0, 0);
                accG[0][nr] = __builtin_amdgcn_mfma_f32_16x16x32_bf16(a0, bg_, accG[0][nr], 0, 0, 0);
                accG[1][nr] = __builtin_amdgcn_mfma_f32_16x16x32_bf16(a1, bg_, accG[1][nr], 0, 0, 0);
            }
        }
        __syncthreads();
    }

    int lr = l >> 4, lc = l & 15;
#pragma unroll
    for (int mr = 0; mr < 2; ++mr) {
#pragma unroll
        for (int nr = 0; nr < 4; ++nr) {
            int n = n0 + nr * 16 + lc;
            float bmv = bm2[n], bgv = bg2[n];
#pragma unroll
            for (int q = 0; q < 4; ++q) {
                int p = p0 + w * 32 + mr * 16 + lr * 4 + q;
                float m = accM[mr][nr][q] + bmv;
                float g = accG[mr][nr][q] + bgv;
                float zv = m / (1.f + __expf(-g));
                z[(size_t)p * NLAT + n] = f2b(zv);
            }
        }
    }
}

// ---------------- out projection via MFMA (K=256) — validated round-6 template
__global__ __launch_bounds__(256) void k_out_mfma(
    const unsigned short* __restrict__ z, const unsigned short* __restrict__ OWB,
    const float* __restrict__ ob, float* __restrict__ out)
{
    __shared__ __align__(16) unsigned short smA[128 * 32];
    __shared__ __align__(16) unsigned short smB[128 * 32];
    int tid = threadIdx.x;
    int w = tid >> 6, l = tid & 63;
    int p0 = blockIdx.x * 128;
    int b = p0 >> 14;
    int l0 = p0 & (LL - 1);

    int rowA = tid >> 2;
    int chA  = tid & 3;
    int laneRow = l & 15;
    int laneK   = l >> 4;

    float4v acc[2][6];
#pragma unroll
    for (int i = 0; i < 2; ++i)
#pragma unroll
        for (int f = 0; f < 6; ++f) acc[i][f] = (float4v)0.f;

    for (int kt = 0; kt < 8; ++kt) {
        const unsigned short* gA = z + (size_t)(p0 + rowA) * 256 + kt * 32 + chA * 8;
        const unsigned short* gB = OWB + (size_t)rowA * 256 + kt * 32 + chA * 8;
        GLL16(gA,            smA + tid * 8);
        GLL16(gA + 64 * 256, smA + 2048 + tid * 8);
        GLL16(gB,            smB + tid * 8);
        GLL16(gB + 64 * 256, smB + 2048 + tid * 8);
        __syncthreads();

        short8v a0 = *(const short8v*)(&smA[(w * 32 + laneRow) * 32 + laneK * 8]);
        short8v a1 = *(const short8v*)(&smA[(w * 32 + 16 + laneRow) * 32 + laneK * 8]);
#pragma unroll
        for (int nr = 0; nr < 6; ++nr) {
            short8v bf_ = *(const short8v*)(&smB[(nr * 16 + laneRow) * 32 + laneK * 8]);
            acc[0][nr] = __builtin_amdgcn_mfma_f32_16x16x32_bf16(a0, bf_, acc[0][nr], 0, 0, 0);
            acc[1][nr] = __builtin_amdgcn_mfma_f32_16x16x32_bf16(a1, bf_, acc[1][nr], 0, 0, 0);
        }
        __syncthreads();
    }

    int lr = l >> 4, lc = l & 15;
#pragma unroll
    for (int mr = 0; mr < 2; ++mr) {
#pragma unroll
        for (int nr = 0; nr < 6; ++nr) {
            int c = nr * 16 + lc;
            float obv = ob[c];
            int ll = l0 + w * 32 + mr * 16 + lr * 4;
            float4 v;
            v.x = acc[mr][nr][0] + obv;
            v.y = acc[mr][nr][1] + obv;
            v.z = acc[mr][nr][2] + obv;
            v.w = acc[mr][nr][3] + obv;
            *(float4*)(&out[((size_t)(b * 96 + c)) * LL + ll]) = v;
        }
    }
}

extern "C" void kernel_launch(void* const* d_in, const int* in_sizes, int n_in,
                              void* d_out, int out_size, void* d_ws, size_t ws_size,
                              hipStream_t stream) {
    (void)in_sizes; (void)n_in; (void)out_size; (void)ws_size;
    const float* x   = (const float*)d_in[0];
    const float* xw  = (const float*)d_in[1];
    const float* xb  = (const float*)d_in[2];
    const float* bcw = (const float*)d_in[3];
    const float* bcb = (const float*)d_in[4];
    const float* dw  = (const float*)d_in[5];
    const float* db  = (const float*)d_in[6];
    const float* yw  = (const float*)d_in[7];
    const float* yb  = (const float*)d_in[8];
    const float* mw  = (const float*)d_in[9];
    const float* mb  = (const float*)d_in[10];
    const float* gw  = (const float*)d_in[11];
    const float* gb  = (const float*)d_in[12];
    const float* ow  = (const float*)d_in[13];
    const float* ob  = (const float*)d_in[14];
    float* out = (float*)d_out;

    char* ws = (char*)d_ws;
    size_t off = 0;
    auto alloc = [&](size_t bytes) -> void* {
        void* p = ws + off;
        off += (bytes + 255) & ~(size_t)255;
        return p;
    };
    unsigned int*   AB  = (unsigned int*)  alloc((size_t)NB * LL * NLAT * 4);
    unsigned short* C   = (unsigned short*)alloc((size_t)NB * LL * NLAT * 2);
    unsigned short* YS  = (unsigned short*)alloc((size_t)NB * 4 * LL * NLAT * 2);
    unsigned short* Z   = (unsigned short*)alloc((size_t)NB * LL * NLAT * 2);
    unsigned short* WBT = (unsigned short*)alloc((size_t)512 * 1024 * 2);
    unsigned short* XT  = (unsigned short*)alloc((size_t)NB * LL * 192 * 2);
    unsigned short* WPT = (unsigned short*)alloc((size_t)1024 * 192 * 2);
    unsigned short* OWB = (unsigned short*)alloc((size_t)128 * 256 * 2);
    float* WF   = (float*)alloc((size_t)4 * 512 * 1024 * 4);
    float* BM2  = (float*)alloc(256 * 4);
    float* BG2  = (float*)alloc(256 * 4);
    float* AggA = (float*)alloc((size_t)NB * 4 * 64 * NLAT * 4);
    float* AggB = (float*)alloc((size_t)NB * 4 * 64 * NLAT * 4);
    float* HS   = (float*)alloc((size_t)NB * 4 * 64 * NLAT * 4);

    k_foldw_part<<<dim3(4, 4, 32),  256, 0, stream>>>(yw, mw, gw, WF);
    k_foldsum   <<<512,             256, 0, stream>>>(WF, WBT);
    k_foldbias  <<<512,              64, 0, stream>>>(mw, gw, mb, gb, yb, BM2, BG2);
    k_wprep     <<<32,              256, 0, stream>>>(xw, bcw, dw, WPT);
    k_owprep    <<<128,              64, 0, stream>>>(ow, OWB);
    k_xpose     <<<512,             256, 0, stream>>>(x, XT);
    k_proj_mfma <<<dim3(256, 8),    256, 0, stream>>>(XT, WPT, xb, bcb, db, AB, C);
    k_scan1     <<<dim3(64, 4, NB), 256, 0, stream>>>(AB, AggA, AggB);
    k_scan2     <<<dim3(4, NB),     256, 0, stream>>>(AggA, AggB, HS);
    k_scan3     <<<dim3(64, 4, NB), 256, 0, stream>>>(AB, C, HS, YS);
    k_merge_mfma<<<dim3(256, 4),    256, 0, stream>>>(YS, WBT, BM2, BG2, Z);
    k_out_mfma  <<<256,             256, 0, stream>>>(Z, OWB, ob, out);
}